// Round 17
// baseline (542.916 us; speedup 1.0000x reference)
//
#include <hip/hip_runtime.h>
#include <hip/hip_bf16.h>

#define DEV __device__ __forceinline__

typedef __attribute__((ext_vector_type(8))) short short8;
typedef __attribute__((ext_vector_type(4))) short short4v;
typedef __attribute__((ext_vector_type(4))) float f32x4;
typedef __attribute__((ext_vector_type(2))) int int2v;

constexpr int Bb   = 4;
constexpr int SEQ  = 2048;
constexpr int C    = 1024;
constexpr int HID  = 4096;
constexpr int NH   = 16;
constexpr int HD   = 64;
constexpr int MTOT = Bb * SEQ;   // 8192 tokens

DEV unsigned bfbits(float f) {
  unsigned x = __float_as_uint(f);
  return (x + 0x7fffu + ((x >> 16) & 1u)) >> 16;   // RNE to bf16, low 16 bits
}

DEV short f2bf(float f) { return (short)bfbits(f); }

// fast bf16 pair pack: +0x8000 (round-half-up, inputs positive finite) + byte perm
DEV unsigned packrn(float a, float b) {
  unsigned ua = __float_as_uint(a) + 0x8000u;
  unsigned ub = __float_as_uint(b) + 0x8000u;
  return __builtin_amdgcn_perm(ub, ua, 0x07060302u);
}

// raw v_exp_f32 (2^x), no OCML denorm guard (flush-to-zero fine for softmax)
DEV float fexp2(float x) {
#if __has_builtin(__builtin_amdgcn_exp2f)
  return __builtin_amdgcn_exp2f(x);
#else
  float r;
  asm("v_exp_f32 %0, %1" : "=v"(r) : "v"(x));
  return r;
#endif
}

DEV void gload16(const void* g, void* l) {
  __builtin_amdgcn_global_load_lds((const __attribute__((address_space(1))) void*)g,
                                   (__attribute__((address_space(3))) void*)l, 16, 0, 0);
}

// 16x16x16 bf16 MFMA (A/B = 2 VGPRs = 4 bf16)
DEV f32x4 mfma16(short4v a, short4v b, f32x4 c) {
#if __has_builtin(__builtin_amdgcn_mfma_f32_16x16x16bf16_1k)
  return __builtin_amdgcn_mfma_f32_16x16x16bf16_1k(a, b, c, 0, 0, 0);
#else
  asm volatile("v_mfma_f32_16x16x16_bf16 %0, %1, %2, %0" : "+v"(c) : "v"(a), "v"(b));
  return c;
#endif
}

// ---------------- weight transpose: fp32 [R][Cc] -> bf16 [Cc][R] ----------------
DEV void transpose_body(const float* __restrict__ src, short* __restrict__ dst,
                        int R, int Cc) {
  __shared__ float t[32][33];
  int tx = threadIdx.x & 31, ty = threadIdx.x >> 5;   // 32 x 8
  int c0 = blockIdx.x * 32, r0 = blockIdx.y * 32;
  #pragma unroll
  for (int i = 0; i < 4; i++)
    t[ty + i * 8][tx] = src[(size_t)(r0 + ty + i * 8) * Cc + c0 + tx];
  __syncthreads();
  #pragma unroll
  for (int i = 0; i < 4; i++)
    dst[(size_t)(c0 + ty + i * 8) * R + r0 + tx] = f2bf(t[tx][ty + i * 8]);
}

__global__ void k_transpose_w(const float* __restrict__ src, short* __restrict__ dst,
                              int R, int Cc) {
  transpose_body(src, dst, R, Cc);
}

// 4 square CxC transposes in one launch (z selects)
__global__ void k_transpose_w4(const float* __restrict__ s0, const float* __restrict__ s1,
                               const float* __restrict__ s2, const float* __restrict__ s3,
                               short* __restrict__ d0, short* __restrict__ d1,
                               short* __restrict__ d2, short* __restrict__ d3) {
  const float* s = blockIdx.z == 0 ? s0 : blockIdx.z == 1 ? s1 : blockIdx.z == 2 ? s2 : s3;
  short*       d = blockIdx.z == 0 ? d0 : blockIdx.z == 1 ? d1 : blockIdx.z == 2 ? d2 : d3;
  transpose_body(s, d, C, C);
}

// ---------------- V transpose: bf16 [tok][C] -> per-(b,h) [HD][SEQ] ----------------
__global__ void k_transpose_v(const short* __restrict__ V, short* __restrict__ Vt) {
  __shared__ short t[32][33];
  int tx = threadIdx.x & 31, ty = threadIdx.x >> 5;
  int plane = blockIdx.z;                 // b*16 + h
  int b = plane >> 4, h = plane & 15;
  int n0 = blockIdx.x * 32, d0 = blockIdx.y * 32;
  #pragma unroll
  for (int i = 0; i < 4; i++)
    t[ty + i * 8][tx] = V[(size_t)(b * SEQ + n0 + ty + i * 8) * C + h * HD + d0 + tx];
  __syncthreads();
  #pragma unroll
  for (int i = 0; i < 4; i++)
    Vt[((size_t)plane * HD + d0 + ty + i * 8) * SEQ + n0 + tx] = t[tx][ty + i * 8];
}

// ---------------- fused LN for q-input (x) and kv-input (x+pos) ----------------
__global__ void k_ln_qkv(const float* __restrict__ x, const float* __restrict__ pos,
                         const float* __restrict__ nqg, const float* __restrict__ nqb,
                         const float* __restrict__ nkg, const float* __restrict__ nkb,
                         const float* __restrict__ nvg, const float* __restrict__ nvb,
                         short* __restrict__ xq, short* __restrict__ xk,
                         short* __restrict__ xv) {
  int row = blockIdx.x, tid = threadIdx.x;
  int n = row & (SEQ - 1);
  float a4[4], p4[4];
  float s1 = 0, s2 = 0, t1 = 0, t2 = 0;
  #pragma unroll
  for (int i = 0; i < 4; i++) {
    int c = tid + i * 256;
    float a = x[(size_t)row * C + c];
    float p = pos[(size_t)n * C + c] + a;
    a4[i] = a; p4[i] = p;
    s1 += a; s2 += a * a; t1 += p; t2 += p * p;
  }
  #pragma unroll
  for (int off = 32; off; off >>= 1) {
    s1 += __shfl_xor(s1, off, 64);
    s2 += __shfl_xor(s2, off, 64);
    t1 += __shfl_xor(t1, off, 64);
    t2 += __shfl_xor(t2, off, 64);
  }
  __shared__ float red[4][4];
  int wave = tid >> 6, lane = tid & 63;
  if (lane == 0) { red[wave][0] = s1; red[wave][1] = s2; red[wave][2] = t1; red[wave][3] = t2; }
  __syncthreads();
  s1 = red[0][0] + red[1][0] + red[2][0] + red[3][0];
  s2 = red[0][1] + red[1][1] + red[2][1] + red[3][1];
  t1 = red[0][2] + red[1][2] + red[2][2] + red[3][2];
  t2 = red[0][3] + red[1][3] + red[2][3] + red[3][3];
  float mq = s1 * (1.f / C), mk = t1 * (1.f / C);
  float rq = rsqrtf(s2 * (1.f / C) - mq * mq + 1e-5f);
  float rk = rsqrtf(t2 * (1.f / C) - mk * mk + 1e-5f);
  #pragma unroll
  for (int i = 0; i < 4; i++) {
    int c = tid + i * 256;
    float nq_ = (a4[i] - mq) * rq;
    float nk_ = (p4[i] - mk) * rk;
    xq[(size_t)row * C + c] = f2bf(nq_ * nqg[c] + nqb[c]);
    xk[(size_t)row * C + c] = f2bf(nk_ * nkg[c] + nkb[c]);
    xv[(size_t)row * C + c] = f2bf(nk_ * nvg[c] + nvb[c]);
  }
}

// ---------------- plain LN (h -> bf16) ----------------
__global__ void k_ln1(const float* __restrict__ h, const float* __restrict__ g,
                      const float* __restrict__ bta, short* __restrict__ out) {
  int row = blockIdx.x, tid = threadIdx.x;
  float a4[4];
  float s1 = 0, s2 = 0;
  #pragma unroll
  for (int i = 0; i < 4; i++) {
    int c = tid + i * 256;
    float a = h[(size_t)row * C + c];
    a4[i] = a; s1 += a; s2 += a * a;
  }
  #pragma unroll
  for (int off = 32; off; off >>= 1) {
    s1 += __shfl_xor(s1, off, 64);
    s2 += __shfl_xor(s2, off, 64);
  }
  __shared__ float red[4][2];
  int wave = tid >> 6, lane = tid & 63;
  if (lane == 0) { red[wave][0] = s1; red[wave][1] = s2; }
  __syncthreads();
  s1 = red[0][0] + red[1][0] + red[2][0] + red[3][0];
  s2 = red[0][1] + red[1][1] + red[2][1] + red[3][1];
  float m = s1 * (1.f / C);
  float r = rsqrtf(s2 * (1.f / C) - m * m + 1e-5f);
  #pragma unroll
  for (int i = 0; i < 4; i++) {
    int c = tid + i * 256;
    out[(size_t)row * C + c] = f2bf((a4[i] - m) * r * g[c] + bta[c]);
  }
}

// ---------------- 8-wave pipelined GEMM body: BM=128 BN=256 BK=64, 3-buffer LDS ------
// Used for N=1024 output shapes (grid 256 blocks = 1/CU; the 256^2 tile would only
// make 128 blocks there — r13 measured that at 10.9% occupancy / +35% wall).
template <int MODE>
DEV void gemm8_body(const short* __restrict__ A, const short* __restrict__ Bt,
                    const float* __restrict__ bias, const float* __restrict__ resid,
                    void* __restrict__ outp, int Nn, int Kk, float scale,
                    int m0, int n0, short* __restrict__ sA, short* __restrict__ sB) {
  constexpr int AO = 128 * 64, BO = 256 * 64;   // shorts per buffer
  const int tid = threadIdx.x;
  const int wave = tid >> 6, lane = tid & 63, quad = lane >> 4, l15 = lane & 15;
  const int wm = (wave >> 2) * 64, wn = (wave & 3) * 64;

  const int sr = tid >> 3, su = tid & 7;
  const int sx = (su ^ (sr & 7)) * 8;                 // (row&7) invariant under +64
  const short* gA0 = A + (size_t)(m0 + sr) * Kk + sx;
  const short* gA1 = gA0 + (size_t)64 * Kk;
  const short* gB0 = Bt + (size_t)(n0 + sr) * Kk + sx;
  const short* gB1 = gB0 + (size_t)64 * Kk;
  const short* gB2 = gB0 + (size_t)128 * Kk;
  const short* gB3 = gB0 + (size_t)192 * Kk;

  const f32x4 fzero = {0.f, 0.f, 0.f, 0.f};
  f32x4 acc[4][4];
  #pragma unroll
  for (int mi = 0; mi < 4; mi++)
    #pragma unroll
    for (int ni = 0; ni < 4; ni++) acc[mi][ni] = fzero;

  const int nkt = Kk >> 6;

  auto stg = [&](int t) {
    const int b_ = t % 3, ko = t << 6;
    gload16(gA0 + ko, &sA[(size_t)b_ * AO + (size_t)tid * 8]);
    gload16(gA1 + ko, &sA[(size_t)b_ * AO + (size_t)(512 + tid) * 8]);
    gload16(gB0 + ko, &sB[(size_t)b_ * BO + (size_t)tid * 8]);
    gload16(gB1 + ko, &sB[(size_t)b_ * BO + (size_t)(512 + tid) * 8]);
    gload16(gB2 + ko, &sB[(size_t)b_ * BO + (size_t)(1024 + tid) * 8]);
    gload16(gB3 + ko, &sB[(size_t)b_ * BO + (size_t)(1536 + tid) * 8]);
  };
  auto stgA_ = [&](int t) {
    const int b_ = t % 3, ko = t << 6;
    gload16(gA0 + ko, &sA[(size_t)b_ * AO + (size_t)tid * 8]);
    gload16(gA1 + ko, &sA[(size_t)b_ * AO + (size_t)(512 + tid) * 8]);
    gload16(gB0 + ko, &sB[(size_t)b_ * BO + (size_t)tid * 8]);
  };
  auto stgB_ = [&](int t) {
    const int b_ = t % 3, ko = t << 6;
    gload16(gB1 + ko, &sB[(size_t)b_ * BO + (size_t)(512 + tid) * 8]);
    gload16(gB2 + ko, &sB[(size_t)b_ * BO + (size_t)(1024 + tid) * 8]);
    gload16(gB3 + ko, &sB[(size_t)b_ * BO + (size_t)(1536 + tid) * 8]);
  };

  stg(0);
  if (nkt > 1) stg(1);

  for (int t = 0; t < nkt; t++) {
    if (t + 1 < nkt) asm volatile("s_waitcnt vmcnt(6)" ::: "memory");
    else             asm volatile("s_waitcnt vmcnt(0)" ::: "memory");
    __builtin_amdgcn_s_barrier();
    const short* a_ = &sA[(size_t)(t % 3) * AO];
    const short* b_ = &sB[(size_t)(t % 3) * BO];
    short8 av[4][2];   // A fragments: read once (phase 0), cached across phase 1
    {
      short8 bv[2][2];
      #pragma unroll
      for (int m2 = 0; m2 < 4; m2++) {
        const int rA = wm + m2 * 16 + l15, sw = rA & 7;
        #pragma unroll
        for (int ks = 0; ks < 2; ks++)
          av[m2][ks] = *(const short8*)&a_[rA * 64 + ((ks * 4 + quad) ^ sw) * 8];
      }
      #pragma unroll
      for (int n2 = 0; n2 < 2; n2++) {
        const int rB = wn + n2 * 16 + l15, sw = rB & 7;
        #pragma unroll
        for (int ks = 0; ks < 2; ks++)
          bv[n2][ks] = *(const short8*)&b_[rB * 64 + ((ks * 4 + quad) ^ sw) * 8];
      }
      if (t + 2 < nkt) stgA_(t + 2);
      __builtin_amdgcn_s_barrier();
      asm volatile("s_waitcnt lgkmcnt(0)" ::: "memory");
      __builtin_amdgcn_sched_barrier(0);
      __builtin_amdgcn_s_setprio(1);
      #pragma unroll
      for (int ks = 0; ks < 2; ks++)
        #pragma unroll
        for (int m2 = 0; m2 < 4; m2++)
          #pragma unroll
          for (int n2 = 0; n2 < 2; n2++)
            acc[m2][n2] = __builtin_amdgcn_mfma_f32_16x16x32_bf16(
                av[m2][ks], bv[n2][ks], acc[m2][n2], 0, 0, 0);
      __builtin_amdgcn_s_setprio(0);
      __builtin_amdgcn_s_barrier();
    }
    {
      short8 bv[2][2];
      #pragma unroll
      for (int n2 = 0; n2 < 2; n2++) {
        const int rB = wn + (2 + n2) * 16 + l15, sw = rB & 7;
        #pragma unroll
        for (int ks = 0; ks < 2; ks++)
          bv[n2][ks] = *(const short8*)&b_[rB * 64 + ((ks * 4 + quad) ^ sw) * 8];
      }
      if (t + 2 < nkt) stgB_(t + 2);
      __builtin_amdgcn_s_barrier();
      asm volatile("s_waitcnt lgkmcnt(0)" ::: "memory");
      __builtin_amdgcn_sched_barrier(0);
      __builtin_amdgcn_s_setprio(1);
      #pragma unroll
      for (int ks = 0; ks < 2; ks++)
        #pragma unroll
        for (int m2 = 0; m2 < 4; m2++)
          #pragma unroll
          for (int n2 = 0; n2 < 2; n2++)
            acc[m2][2 + n2] = __builtin_amdgcn_mfma_f32_16x16x32_bf16(
                av[m2][ks], bv[n2][ks], acc[m2][2 + n2], 0, 0, 0);
      __builtin_amdgcn_s_setprio(0);
      __builtin_amdgcn_s_barrier();
    }
  }

  float bb[4];
  #pragma unroll
  for (int ni = 0; ni < 4; ni++) bb[ni] = bias[n0 + wn + ni * 16 + l15];
  #pragma unroll
  for (int mi = 0; mi < 4; mi++) {
    #pragma unroll
    for (int ni = 0; ni < 4; ni++) {
      #pragma unroll
      for (int r = 0; r < 4; r++) {
        int row = m0 + wm + mi * 16 + quad * 4 + r;
        int col = n0 + wn + ni * 16 + l15;
        float v = (acc[mi][ni][r] + bb[ni]) * scale;
        if constexpr (MODE == 1) v = v >= 0.f ? v : 0.1f * v;
        if constexpr (MODE == 2)
          ((float*)outp)[(size_t)row * Nn + col] = resid[(size_t)row * Nn + col] + v;
        else
          ((short*)outp)[(size_t)row * Nn + col] = f2bf(v);
      }
    }
  }
}

template <int MODE>
__global__ __launch_bounds__(512, 1)
void k_gemm8(const short* __restrict__ A, const short* __restrict__ Bt,
             const float* __restrict__ bias, const float* __restrict__ resid,
             void* __restrict__ outp, int Nn, int Kk) {
  __shared__ __align__(16) short sA[3 * 128 * 64];   // 48 KB
  __shared__ __align__(16) short sB[3 * 256 * 64];   // 96 KB
  gemm8_body<MODE>(A, Bt, bias, resid, outp, Nn, Kk, 1.0f,
                   blockIdx.x * 128, blockIdx.y * 256, sA, sB);
}

// ---------------- 256x256-tile 8-wave GEMM (r13-verified): BK=64, 2-buffer LDS ------
// 30% better per-work than gemm8 (r13: 1.95us per 2x-work tile vs 1.40). Use ONLY
// where the grid makes >= 256 blocks (N>=2048 outputs or z-stacked).
template <int MODE>
DEV void gemm2_body(const short* __restrict__ A, const short* __restrict__ Bt,
                    const float* __restrict__ bias, const float* __restrict__ resid,
                    void* __restrict__ outp, int Nn, int Kk, float scale,
                    int m0, int n0, short* __restrict__ sA, short* __restrict__ sB) {
  constexpr int TO = 256 * 64;   // shorts per tile buffer (A or B)
  const int tid = threadIdx.x;
  const int wave = tid >> 6, lane = tid & 63, quad = lane >> 4, l15 = lane & 15;
  const int wm = (wave >> 2) * 128, wn = (wave & 3) * 64;

  const int sr = tid >> 3, su = tid & 7;
  const int sx = (su ^ (sr & 7)) * 8;                 // (row&7) invariant under +64
  const short* gA0 = A + (size_t)(m0 + sr) * Kk + sx;
  const short* gB0 = Bt + (size_t)(n0 + sr) * Kk + sx;

  const f32x4 fzero = {0.f, 0.f, 0.f, 0.f};
  f32x4 acc[8][4];
  #pragma unroll
  for (int mi = 0; mi < 8; mi++)
    #pragma unroll
    for (int ni = 0; ni < 4; ni++) acc[mi][ni] = fzero;

  const int nkt = Kk >> 6;

  auto stgPair = [&](int t, int p) {
    const int b_ = t & 1, ko = t << 6;
    gload16(gA0 + (size_t)(p * 64) * Kk + ko,
            &sA[(size_t)b_ * TO + (size_t)p * 4096 + (size_t)tid * 8]);
    gload16(gB0 + (size_t)(p * 64) * Kk + ko,
            &sB[(size_t)b_ * TO + (size_t)p * 4096 + (size_t)tid * 8]);
  };

  #pragma unroll
  for (int p = 0; p < 4; p++) stgPair(0, p);

  for (int t = 0; t < nkt; t++) {
    asm volatile("s_waitcnt vmcnt(0)" ::: "memory");
    __builtin_amdgcn_s_barrier();
    const short* a_ = &sA[(size_t)(t & 1) * TO];
    const short* b_ = &sB[(size_t)(t & 1) * TO];
    short8 bv[4][2];   // B fragments: read once (phase 0), cached across phases 1-3
    #pragma unroll
    for (int ph = 0; ph < 4; ph++) {
      short8 av[2][2];
      #pragma unroll
      for (int m2 = 0; m2 < 2; m2++) {
        const int rA = wm + (ph * 2 + m2) * 16 + l15, sw = rA & 7;
        #pragma unroll
        for (int ks = 0; ks < 2; ks++)
          av[m2][ks] = *(const short8*)&a_[rA * 64 + ((ks * 4 + quad) ^ sw) * 8];
      }
      if (ph == 0) {
        #pragma unroll
        for (int n2 = 0; n2 < 4; n2++) {
          const int rB = wn + n2 * 16 + l15, sw = rB & 7;
          #pragma unroll
          for (int ks = 0; ks < 2; ks++)
            bv[n2][ks] = *(const short8*)&b_[rB * 64 + ((ks * 4 + quad) ^ sw) * 8];
        }
      }
      if (t + 1 < nkt) stgPair(t + 1, ph);
      __builtin_amdgcn_s_barrier();
      asm volatile("s_waitcnt lgkmcnt(0)" ::: "memory");
      __builtin_amdgcn_sched_barrier(0);
      __builtin_amdgcn_s_setprio(1);
      #pragma unroll
      for (int ks = 0; ks < 2; ks++)
        #pragma unroll
        for (int m2 = 0; m2 < 2; m2++)
          #pragma unroll
          for (int n2 = 0; n2 < 4; n2++)
            acc[ph * 2 + m2][n2] = __builtin_amdgcn_mfma_f32_16x16x32_bf16(
                av[m2][ks], bv[n2][ks], acc[ph * 2 + m2][n2], 0, 0, 0);
      __builtin_amdgcn_s_setprio(0);
      __builtin_amdgcn_s_barrier();
    }
  }

  float bb[4];
  #pragma unroll
  for (int ni = 0; ni < 4; ni++) bb[ni] = bias[n0 + wn + ni * 16 + l15];
  #pragma unroll
  for (int mi = 0; mi < 8; mi++) {
    #pragma unroll
    for (int ni = 0; ni < 4; ni++) {
      #pragma unroll
      for (int r = 0; r < 4; r++) {
        int row = m0 + wm + mi * 16 + quad * 4 + r;
        int col = n0 + wn + ni * 16 + l15;
        float v = (acc[mi][ni][r] + bb[ni]) * scale;
        if constexpr (MODE == 1) v = v >= 0.f ? v : 0.1f * v;
        if constexpr (MODE == 2)
          ((float*)outp)[(size_t)row * Nn + col] = resid[(size_t)row * Nn + col] + v;
        else
          ((short*)outp)[(size_t)row * Nn + col] = f2bf(v);
      }
    }
  }
}

template <int MODE>
__global__ __launch_bounds__(512, 1)
void k_gemm2(const short* __restrict__ A, const short* __restrict__ Bt,
             const float* __restrict__ bias, const float* __restrict__ resid,
             void* __restrict__ outp, int Nn, int Kk) {
  __shared__ __align__(16) short sA[2 * 256 * 64];   // 64 KB
  __shared__ __align__(16) short sB[2 * 256 * 64];   // 64 KB
  gemm2_body<MODE>(A, Bt, bias, resid, outp, Nn, Kk, 1.0f,
                   blockIdx.x * 256, blockIdx.y * 256, sA, sB);
}

// fused QKV projection on the gemm2 structure: z selects {xq->Qm (scaled), xk->Km, xv->Vm}
__global__ __launch_bounds__(512, 1)
void k_gemm2_qkv(const short* __restrict__ xq, const short* __restrict__ xk,
                 const short* __restrict__ xv,
                 const short* __restrict__ wqT, const short* __restrict__ wkT,
                 const short* __restrict__ wvT,
                 const float* __restrict__ bq, const float* __restrict__ bk,
                 const float* __restrict__ bv,
                 short* __restrict__ Qm, short* __restrict__ Km, short* __restrict__ Vm) {
  __shared__ __align__(16) short sA[2 * 256 * 64];
  __shared__ __align__(16) short sB[2 * 256 * 64];
  const int z = blockIdx.z;
  const short* A    = z == 0 ? xq : z == 1 ? xk : xv;
  const short* Bt   = z == 0 ? wqT : z == 1 ? wkT : wvT;
  const float* bias = z == 0 ? bq : z == 1 ? bk : bv;
  short* outp       = z == 0 ? Qm : z == 1 ? Km : Vm;
  const float scale = z == 0 ? 0.1803368801111244f : 1.0f;   // 0.125 * log2(e) on Q
  gemm2_body<0>(A, Bt, bias, nullptr, outp, C, C, scale,
                blockIdx.x * 256, blockIdx.y * 256, sA, sB);
}

// ---------------- flash attention, S^T formulation, 8-wave (16 q-rows/wave) ----------------
// r14: 512-thread blocks -> 32 waves/CU (was 16) to co-issue MFMA+VALU across waves
// (both pipes measured ~50% busy at 4-wave blocks); K/V LDS tile amortized by 8 waves.
// T5 setprio around MFMA clusters (m191: +4-7% attn).
__global__ __launch_bounds__(512, 8)
void k_attn(const short* __restrict__ Q, const short* __restrict__ K,
            const short* __restrict__ Vt, short* __restrict__ O) {
  __shared__ __align__(16) short sK[2][64 * 64];
  __shared__ __align__(16) short sV[2][64 * 64];   // Vt tile: [d][key]
  const int tid = threadIdx.x;
  const int bh = blockIdx.x;                        // bh fastest -> XCD-pinned K/V reuse
  const int b = bh >> 4, h = bh & 15;
  const int q0 = blockIdx.y * 128;
  const int wave = tid >> 6, lane = tid & 63, quad = lane >> 4, l15 = lane & 15;
  const int wm = wave * 16;        // 16 q-rows per wave, 8 waves
  const size_t tokBase = (size_t)b * SEQ;

  // Q fragments in registers (B-operand of QK^T): [d-half]
  short8 qf[2];
  #pragma unroll
  for (int hf = 0; hf < 2; hf++)
    qf[hf] = *(const short8*)(Q + (tokBase + q0 + wm + l15) * C
                              + h * HD + hf * 32 + quad * 8);

  // staging: 512 threads, 8 per row (16B each); pre-swizzled source col (rule #21)
  const int r0 = tid >> 3, c0s = ((tid & 7) ^ (r0 & 7)) * 8;
  const short* gK0 = K + (tokBase + r0) * C + h * HD + c0s;
  const short* gV0 = Vt + ((size_t)bh * HD + r0) * SEQ + c0s;
  short* lK0 = &sK[0][tid * 8];
  short* lV0 = &sV[0][tid * 8];
  constexpr int BUFO = 64 * 64;   // shorts per buffer

#define STAGE(bufsel, kb) {                                   \
    int kk = (kb) * 64, bo = (bufsel) * BUFO;                 \
    gload16(gK0 + (size_t)kk * C, lK0 + bo);                  \
    gload16(gV0 + kk,             lV0 + bo); }

  const f32x4 fzero = {0.f, 0.f, 0.f, 0.f};
  const short4v onesv = {0x3F80, 0x3F80, 0x3F80, 0x3F80};   // bf16 1.0 x4
  f32x4 o[4];
  f32x4 oSum = fzero;
  #pragma unroll
  for (int di = 0; di < 4; di++) o[di] = fzero;

  const int sw = l15 & 7;                    // seg swizzle key

  STAGE(0, 0)

  for (int kb = 0; kb < SEQ / 64; kb++) {
    const int buf = kb & 1;
    __syncthreads();
    if (kb + 1 < SEQ / 64) STAGE(buf ^ 1, kb + 1)

    unsigned pk[4][2];
    #pragma unroll
    for (int ki = 0; ki < 4; ki++) {
      const int krow = (ki * 16 + l15) * 64;
      short8 a0 = *(const short8*)&sK[buf][krow + ((0 + quad) ^ sw) * 8];
      short8 a1 = *(const short8*)&sK[buf][krow + ((4 + quad) ^ sw) * 8];
      __builtin_amdgcn_s_setprio(1);
      f32x4 st = __builtin_amdgcn_mfma_f32_16x16x32_bf16(a0, qf[0], fzero, 0, 0, 0);
      st = __builtin_amdgcn_mfma_f32_16x16x32_bf16(a1, qf[1], st, 0, 0, 0);
      __builtin_amdgcn_s_setprio(0);
      float p0 = fexp2(st[0]), p1 = fexp2(st[1]);
      float p2 = fexp2(st[2]), p3 = fexp2(st[3]);
      pk[ki][0] = packrn(p0, p1);
      pk[ki][1] = packrn(p2, p3);
    }

    #pragma unroll
    for (int ki = 0; ki < 4; ki++) {
      short4v bv[4];
      const int g = ((ki * 2 + (quad >> 1)) ^ sw) * 8 + (quad & 1) * 4;
      #pragma unroll
      for (int di = 0; di < 4; di++)
        bv[di] = *(const short4v*)&sV[buf][(di * 16 + l15) * 64 + g];
      int2v t; t.x = (int)pk[ki][0]; t.y = (int)pk[ki][1];
      short4v aP = __builtin_bit_cast(short4v, t);
      __builtin_amdgcn_s_setprio(1);
      oSum = mfma16(aP, onesv, oSum);
      #pragma unroll
      for (int di = 0; di < 4; di++)
        o[di] = mfma16(aP, bv[di], o[di]);
      __builtin_amdgcn_s_setprio(0);
    }
  }
#undef STAGE

  float linv[4];
  #pragma unroll
  for (int r = 0; r < 4; r++)
    linv[r] = 1.0f / oSum[r];

  #pragma unroll
  for (int di = 0; di < 4; di++)
    #pragma unroll
    for (int r = 0; r < 4; r++) {
      int row = q0 + wm + quad * 4 + r;
      int col = h * HD + di * 16 + l15;
      O[(tokBase + row) * C + col] = f2bf(o[di][r] * linv[r]);
    }
}

extern "C" void kernel_launch(void* const* d_in, const int* in_sizes, int n_in,
                              void* d_out, int out_size, void* d_ws, size_t ws_size,
                              hipStream_t stream) {
  const float* x   = (const float*)d_in[0];
  const float* pos = (const float*)d_in[1];
  const float* nqg = (const float*)d_in[2];
  const float* nqb = (const float*)d_in[3];
  const float* nkg = (const float*)d_in[4];
  const float* nkb = (const float*)d_in[5];
  const float* nvg = (const float*)d_in[6];
  const float* nvb = (const float*)d_in[7];
  const float* ng  = (const float*)d_in[8];
  const float* nb  = (const float*)d_in[9];
  const float* wq  = (const float*)d_in[10];
  const float* bq  = (const float*)d_in[11];
  const float* wk  = (const float*)d_in[12];
  const float* bk  = (const float*)d_in[13];
  const float* wv  = (const float*)d_in[14];
  const float* bv  = (const float*)d_in[15];
  const float* wp  = (const float*)d_in[16];
  const float* bp  = (const float*)d_in[17];
  const float* w1  = (const float*)d_in[18];
  const float* b1  = (const float*)d_in[19];
  const float* w2  = (const float*)d_in[20];
  const float* b2  = (const float*)d_in[21];

  char* ws = (char*)d_ws;
  const size_t MB = 1u << 20;
  short* wqT  = (short*)(ws + 0 * MB);
  short* wkT  = (short*)(ws + 2 * MB);
  short* wvT  = (short*)(ws + 4 * MB);
  short* wpT  = (short*)(ws + 6 * MB);
  short* w1T  = (short*)(ws + 8 * MB);     // [HID][C]
  short* w2T  = (short*)(ws + 16 * MB);    // [C][HID]
  short* xq   = (short*)(ws + 24 * MB);
  short* xk   = (short*)(ws + 40 * MB);
  short* xv   = (short*)(ws + 56 * MB);
  short* Qm   = (short*)(ws + 72 * MB);
  short* Km   = (short*)(ws + 88 * MB);
  short* Vm   = (short*)(ws + 104 * MB);
  short* Vt   = (short*)(ws + 120 * MB);
  short* y1   = (short*)(ws + 72 * MB);    // overlays Q/K/V/Vt (dead after attn)
  short* Ob   = xk;                         // overlays xk (dead after K-proj)
  short* hln  = xq;                         // overlays xq (dead after Q-proj)
  float* hbuf = (float*)(ws + 136 * MB);
  (void)ws_size; (void)in_sizes; (void)n_in; (void)out_size;

  dim3 blk(256);
  k_transpose_w4<<<dim3(32, 32, 4), blk, 0, stream>>>(wq, wk, wv, wp, wqT, wkT, wvT, wpT);
  k_transpose_w<<<dim3(128, 32), blk, 0, stream>>>(w1, w1T, C, HID);
  k_transpose_w<<<dim3(32, 128), blk, 0, stream>>>(w2, w2T, HID, C);
  k_ln_qkv<<<dim3(MTOT), blk, 0, stream>>>(x, pos, nqg, nqb, nkg, nkb, nvg, nvb, xq, xk, xv);
  // QKV: gemm2 (z-stack gives 384 blocks; 2x-work tiles -> effective 3 work-rounds).
  k_gemm2_qkv<<<dim3(MTOT / 256, C / 256, 3), dim3(512), 0, stream>>>(
      xq, xk, xv, wqT, wkT, wvT, bq, bk, bv, Qm, Km, Vm);
  k_transpose_v<<<dim3(SEQ / 32, HD / 32, Bb * NH), blk, 0, stream>>>(Vm, Vt);
  // attn: 512-thread blocks (8 waves x 16 q-rows), grid unchanged -> 32 waves/CU.
  k_attn<<<dim3(Bb * NH, SEQ / 128), dim3(512), 0, stream>>>(Qm, Km, Vt, Ob);
  // wp (N=1024): gemm8 — 256 blocks = 1/CU (gemm2 would starve at 128).
  k_gemm8<2><<<dim3(MTOT / 128, C / 256), dim3(512), 0, stream>>>(Ob, wpT, bp, x, hbuf, C, C);
  k_ln1<<<dim3(MTOT), blk, 0, stream>>>(hbuf, ng, nb, hln);
  // MLP1 (N=4096): gemm2 — 512 blocks = 2 full rounds of 2x-efficient tiles.
  k_gemm2<1><<<dim3(MTOT / 256, HID / 256), dim3(512), 0, stream>>>(hln, w1T, b1, nullptr,
                                                                    y1, HID, C);
  // MLP2 (N=1024): gemm8 — 256 blocks = 1/CU.
  k_gemm8<2><<<dim3(MTOT / 128, C / 256), dim3(512), 0, stream>>>(y1, w2T, b2, hbuf,
                                                                  (float*)d_out, C, HID);
}

// Round 18
// 529.902 us; speedup vs baseline: 1.0246x; 1.0246x over previous
//
#include <hip/hip_runtime.h>
#include <hip/hip_bf16.h>

#define DEV __device__ __forceinline__

typedef __attribute__((ext_vector_type(8))) short short8;
typedef __attribute__((ext_vector_type(4))) short short4v;
typedef __attribute__((ext_vector_type(4))) float f32x4;
typedef __attribute__((ext_vector_type(2))) int int2v;

constexpr int Bb   = 4;
constexpr int SEQ  = 2048;
constexpr int C    = 1024;
constexpr int HID  = 4096;
constexpr int NH   = 16;
constexpr int HD   = 64;
constexpr int MTOT = Bb * SEQ;   // 8192 tokens

DEV unsigned bfbits(float f) {
  unsigned x = __float_as_uint(f);
  return (x + 0x7fffu + ((x >> 16) & 1u)) >> 16;   // RNE to bf16, low 16 bits
}

DEV short f2bf(float f) { return (short)bfbits(f); }

// fast bf16 pair pack: +0x8000 (round-half-up, inputs positive finite) + byte perm
DEV unsigned packrn(float a, float b) {
  unsigned ua = __float_as_uint(a) + 0x8000u;
  unsigned ub = __float_as_uint(b) + 0x8000u;
  return __builtin_amdgcn_perm(ub, ua, 0x07060302u);
}

// raw v_exp_f32 (2^x), no OCML denorm guard (flush-to-zero fine for softmax)
DEV float fexp2(float x) {
#if __has_builtin(__builtin_amdgcn_exp2f)
  return __builtin_amdgcn_exp2f(x);
#else
  float r;
  asm("v_exp_f32 %0, %1" : "=v"(r) : "v"(x));
  return r;
#endif
}

DEV void gload16(const void* g, void* l) {
  __builtin_amdgcn_global_load_lds((const __attribute__((address_space(1))) void*)g,
                                   (__attribute__((address_space(3))) void*)l, 16, 0, 0);
}

// 16x16x16 bf16 MFMA (A/B = 2 VGPRs = 4 bf16)
DEV f32x4 mfma16(short4v a, short4v b, f32x4 c) {
#if __has_builtin(__builtin_amdgcn_mfma_f32_16x16x16bf16_1k)
  return __builtin_amdgcn_mfma_f32_16x16x16bf16_1k(a, b, c, 0, 0, 0);
#else
  asm volatile("v_mfma_f32_16x16x16_bf16 %0, %1, %2, %0" : "+v"(c) : "v"(a), "v"(b));
  return c;
#endif
}

// ---------------- weight transpose: fp32 [R][Cc] -> bf16 [Cc][R] ----------------
DEV void transpose_body(const float* __restrict__ src, short* __restrict__ dst,
                        int R, int Cc) {
  __shared__ float t[32][33];
  int tx = threadIdx.x & 31, ty = threadIdx.x >> 5;   // 32 x 8
  int c0 = blockIdx.x * 32, r0 = blockIdx.y * 32;
  #pragma unroll
  for (int i = 0; i < 4; i++)
    t[ty + i * 8][tx] = src[(size_t)(r0 + ty + i * 8) * Cc + c0 + tx];
  __syncthreads();
  #pragma unroll
  for (int i = 0; i < 4; i++)
    dst[(size_t)(c0 + ty + i * 8) * R + r0 + tx] = f2bf(t[tx][ty + i * 8]);
}

__global__ void k_transpose_w(const float* __restrict__ src, short* __restrict__ dst,
                              int R, int Cc) {
  transpose_body(src, dst, R, Cc);
}

// 4 square CxC transposes in one launch (z selects)
__global__ void k_transpose_w4(const float* __restrict__ s0, const float* __restrict__ s1,
                               const float* __restrict__ s2, const float* __restrict__ s3,
                               short* __restrict__ d0, short* __restrict__ d1,
                               short* __restrict__ d2, short* __restrict__ d3) {
  const float* s = blockIdx.z == 0 ? s0 : blockIdx.z == 1 ? s1 : blockIdx.z == 2 ? s2 : s3;
  short*       d = blockIdx.z == 0 ? d0 : blockIdx.z == 1 ? d1 : blockIdx.z == 2 ? d2 : d3;
  transpose_body(s, d, C, C);
}

// ---------------- V transpose: bf16 [tok][C] -> per-(b,h) [HD][SEQ] ----------------
__global__ void k_transpose_v(const short* __restrict__ V, short* __restrict__ Vt) {
  __shared__ short t[32][33];
  int tx = threadIdx.x & 31, ty = threadIdx.x >> 5;
  int plane = blockIdx.z;                 // b*16 + h
  int b = plane >> 4, h = plane & 15;
  int n0 = blockIdx.x * 32, d0 = blockIdx.y * 32;
  #pragma unroll
  for (int i = 0; i < 4; i++)
    t[ty + i * 8][tx] = V[(size_t)(b * SEQ + n0 + ty + i * 8) * C + h * HD + d0 + tx];
  __syncthreads();
  #pragma unroll
  for (int i = 0; i < 4; i++)
    Vt[((size_t)plane * HD + d0 + ty + i * 8) * SEQ + n0 + tx] = t[tx][ty + i * 8];
}

// ---------------- fused LN for q-input (x) and kv-input (x+pos) ----------------
__global__ void k_ln_qkv(const float* __restrict__ x, const float* __restrict__ pos,
                         const float* __restrict__ nqg, const float* __restrict__ nqb,
                         const float* __restrict__ nkg, const float* __restrict__ nkb,
                         const float* __restrict__ nvg, const float* __restrict__ nvb,
                         short* __restrict__ xq, short* __restrict__ xk,
                         short* __restrict__ xv) {
  int row = blockIdx.x, tid = threadIdx.x;
  int n = row & (SEQ - 1);
  float a4[4], p4[4];
  float s1 = 0, s2 = 0, t1 = 0, t2 = 0;
  #pragma unroll
  for (int i = 0; i < 4; i++) {
    int c = tid + i * 256;
    float a = x[(size_t)row * C + c];
    float p = pos[(size_t)n * C + c] + a;
    a4[i] = a; p4[i] = p;
    s1 += a; s2 += a * a; t1 += p; t2 += p * p;
  }
  #pragma unroll
  for (int off = 32; off; off >>= 1) {
    s1 += __shfl_xor(s1, off, 64);
    s2 += __shfl_xor(s2, off, 64);
    t1 += __shfl_xor(t1, off, 64);
    t2 += __shfl_xor(t2, off, 64);
  }
  __shared__ float red[4][4];
  int wave = tid >> 6, lane = tid & 63;
  if (lane == 0) { red[wave][0] = s1; red[wave][1] = s2; red[wave][2] = t1; red[wave][3] = t2; }
  __syncthreads();
  s1 = red[0][0] + red[1][0] + red[2][0] + red[3][0];
  s2 = red[0][1] + red[1][1] + red[2][1] + red[3][1];
  t1 = red[0][2] + red[1][2] + red[2][2] + red[3][2];
  t2 = red[0][3] + red[1][3] + red[2][3] + red[3][3];
  float mq = s1 * (1.f / C), mk = t1 * (1.f / C);
  float rq = rsqrtf(s2 * (1.f / C) - mq * mq + 1e-5f);
  float rk = rsqrtf(t2 * (1.f / C) - mk * mk + 1e-5f);
  #pragma unroll
  for (int i = 0; i < 4; i++) {
    int c = tid + i * 256;
    float nq_ = (a4[i] - mq) * rq;
    float nk_ = (p4[i] - mk) * rk;
    xq[(size_t)row * C + c] = f2bf(nq_ * nqg[c] + nqb[c]);
    xk[(size_t)row * C + c] = f2bf(nk_ * nkg[c] + nkb[c]);
    xv[(size_t)row * C + c] = f2bf(nk_ * nvg[c] + nvb[c]);
  }
}

// ---------------- plain LN (h -> bf16) ----------------
__global__ void k_ln1(const float* __restrict__ h, const float* __restrict__ g,
                      const float* __restrict__ bta, short* __restrict__ out) {
  int row = blockIdx.x, tid = threadIdx.x;
  float a4[4];
  float s1 = 0, s2 = 0;
  #pragma unroll
  for (int i = 0; i < 4; i++) {
    int c = tid + i * 256;
    float a = h[(size_t)row * C + c];
    a4[i] = a; s1 += a; s2 += a * a;
  }
  #pragma unroll
  for (int off = 32; off; off >>= 1) {
    s1 += __shfl_xor(s1, off, 64);
    s2 += __shfl_xor(s2, off, 64);
  }
  __shared__ float red[4][2];
  int wave = tid >> 6, lane = tid & 63;
  if (lane == 0) { red[wave][0] = s1; red[wave][1] = s2; }
  __syncthreads();
  s1 = red[0][0] + red[1][0] + red[2][0] + red[3][0];
  s2 = red[0][1] + red[1][1] + red[2][1] + red[3][1];
  float m = s1 * (1.f / C);
  float r = rsqrtf(s2 * (1.f / C) - m * m + 1e-5f);
  #pragma unroll
  for (int i = 0; i < 4; i++) {
    int c = tid + i * 256;
    out[(size_t)row * C + c] = f2bf((a4[i] - m) * r * g[c] + bta[c]);
  }
}

// ---------------- 8-wave pipelined GEMM body: BM=128 BN=256 BK=64, 3-buffer LDS ------
template <int MODE>
DEV void gemm8_body(const short* __restrict__ A, const short* __restrict__ Bt,
                    const float* __restrict__ bias, const float* __restrict__ resid,
                    void* __restrict__ outp, int Nn, int Kk, float scale,
                    int m0, int n0, short* __restrict__ sA, short* __restrict__ sB) {
  constexpr int AO = 128 * 64, BO = 256 * 64;   // shorts per buffer
  const int tid = threadIdx.x;
  const int wave = tid >> 6, lane = tid & 63, quad = lane >> 4, l15 = lane & 15;
  const int wm = (wave >> 2) * 64, wn = (wave & 3) * 64;

  const int sr = tid >> 3, su = tid & 7;
  const int sx = (su ^ (sr & 7)) * 8;                 // (row&7) invariant under +64
  const short* gA0 = A + (size_t)(m0 + sr) * Kk + sx;
  const short* gA1 = gA0 + (size_t)64 * Kk;
  const short* gB0 = Bt + (size_t)(n0 + sr) * Kk + sx;
  const short* gB1 = gB0 + (size_t)64 * Kk;
  const short* gB2 = gB0 + (size_t)128 * Kk;
  const short* gB3 = gB0 + (size_t)192 * Kk;

  const f32x4 fzero = {0.f, 0.f, 0.f, 0.f};
  f32x4 acc[4][4];
  #pragma unroll
  for (int mi = 0; mi < 4; mi++)
    #pragma unroll
    for (int ni = 0; ni < 4; ni++) acc[mi][ni] = fzero;

  const int nkt = Kk >> 6;

  auto stg = [&](int t) {
    const int b_ = t % 3, ko = t << 6;
    gload16(gA0 + ko, &sA[(size_t)b_ * AO + (size_t)tid * 8]);
    gload16(gA1 + ko, &sA[(size_t)b_ * AO + (size_t)(512 + tid) * 8]);
    gload16(gB0 + ko, &sB[(size_t)b_ * BO + (size_t)tid * 8]);
    gload16(gB1 + ko, &sB[(size_t)b_ * BO + (size_t)(512 + tid) * 8]);
    gload16(gB2 + ko, &sB[(size_t)b_ * BO + (size_t)(1024 + tid) * 8]);
    gload16(gB3 + ko, &sB[(size_t)b_ * BO + (size_t)(1536 + tid) * 8]);
  };
  auto stgA_ = [&](int t) {
    const int b_ = t % 3, ko = t << 6;
    gload16(gA0 + ko, &sA[(size_t)b_ * AO + (size_t)tid * 8]);
    gload16(gA1 + ko, &sA[(size_t)b_ * AO + (size_t)(512 + tid) * 8]);
    gload16(gB0 + ko, &sB[(size_t)b_ * BO + (size_t)tid * 8]);
  };
  auto stgB_ = [&](int t) {
    const int b_ = t % 3, ko = t << 6;
    gload16(gB1 + ko, &sB[(size_t)b_ * BO + (size_t)(512 + tid) * 8]);
    gload16(gB2 + ko, &sB[(size_t)b_ * BO + (size_t)(1024 + tid) * 8]);
    gload16(gB3 + ko, &sB[(size_t)b_ * BO + (size_t)(1536 + tid) * 8]);
  };

  stg(0);
  if (nkt > 1) stg(1);

  for (int t = 0; t < nkt; t++) {
    if (t + 1 < nkt) asm volatile("s_waitcnt vmcnt(6)" ::: "memory");
    else             asm volatile("s_waitcnt vmcnt(0)" ::: "memory");
    __builtin_amdgcn_s_barrier();
    const short* a_ = &sA[(size_t)(t % 3) * AO];
    const short* b_ = &sB[(size_t)(t % 3) * BO];
    short8 av[4][2];   // A fragments: read once (phase 0), cached across phase 1
    {
      short8 bv[2][2];
      #pragma unroll
      for (int m2 = 0; m2 < 4; m2++) {
        const int rA = wm + m2 * 16 + l15, sw = rA & 7;
        #pragma unroll
        for (int ks = 0; ks < 2; ks++)
          av[m2][ks] = *(const short8*)&a_[rA * 64 + ((ks * 4 + quad) ^ sw) * 8];
      }
      #pragma unroll
      for (int n2 = 0; n2 < 2; n2++) {
        const int rB = wn + n2 * 16 + l15, sw = rB & 7;
        #pragma unroll
        for (int ks = 0; ks < 2; ks++)
          bv[n2][ks] = *(const short8*)&b_[rB * 64 + ((ks * 4 + quad) ^ sw) * 8];
      }
      if (t + 2 < nkt) stgA_(t + 2);
      __builtin_amdgcn_s_barrier();
      asm volatile("s_waitcnt lgkmcnt(0)" ::: "memory");
      __builtin_amdgcn_sched_barrier(0);
      __builtin_amdgcn_s_setprio(1);
      #pragma unroll
      for (int ks = 0; ks < 2; ks++)
        #pragma unroll
        for (int m2 = 0; m2 < 4; m2++)
          #pragma unroll
          for (int n2 = 0; n2 < 2; n2++)
            acc[m2][n2] = __builtin_amdgcn_mfma_f32_16x16x32_bf16(
                av[m2][ks], bv[n2][ks], acc[m2][n2], 0, 0, 0);
      __builtin_amdgcn_s_setprio(0);
      __builtin_amdgcn_s_barrier();
    }
    {
      short8 bv[2][2];
      #pragma unroll
      for (int n2 = 0; n2 < 2; n2++) {
        const int rB = wn + (2 + n2) * 16 + l15, sw = rB & 7;
        #pragma unroll
        for (int ks = 0; ks < 2; ks++)
          bv[n2][ks] = *(const short8*)&b_[rB * 64 + ((ks * 4 + quad) ^ sw) * 8];
      }
      if (t + 2 < nkt) stgB_(t + 2);
      __builtin_amdgcn_s_barrier();
      asm volatile("s_waitcnt lgkmcnt(0)" ::: "memory");
      __builtin_amdgcn_sched_barrier(0);
      __builtin_amdgcn_s_setprio(1);
      #pragma unroll
      for (int ks = 0; ks < 2; ks++)
        #pragma unroll
        for (int m2 = 0; m2 < 4; m2++)
          #pragma unroll
          for (int n2 = 0; n2 < 2; n2++)
            acc[m2][2 + n2] = __builtin_amdgcn_mfma_f32_16x16x32_bf16(
                av[m2][ks], bv[n2][ks], acc[m2][2 + n2], 0, 0, 0);
      __builtin_amdgcn_s_setprio(0);
      __builtin_amdgcn_s_barrier();
    }
  }

  float bb[4];
  #pragma unroll
  for (int ni = 0; ni < 4; ni++) bb[ni] = bias[n0 + wn + ni * 16 + l15];
  #pragma unroll
  for (int mi = 0; mi < 4; mi++) {
    #pragma unroll
    for (int ni = 0; ni < 4; ni++) {
      #pragma unroll
      for (int r = 0; r < 4; r++) {
        int row = m0 + wm + mi * 16 + quad * 4 + r;
        int col = n0 + wn + ni * 16 + l15;
        float v = (acc[mi][ni][r] + bb[ni]) * scale;
        if constexpr (MODE == 1) v = v >= 0.f ? v : 0.1f * v;
        if constexpr (MODE == 2)
          ((float*)outp)[(size_t)row * Nn + col] = resid[(size_t)row * Nn + col] + v;
        else
          ((short*)outp)[(size_t)row * Nn + col] = f2bf(v);
      }
    }
  }
}

template <int MODE>
__global__ __launch_bounds__(512, 1)
void k_gemm8(const short* __restrict__ A, const short* __restrict__ Bt,
             const float* __restrict__ bias, const float* __restrict__ resid,
             void* __restrict__ outp, int Nn, int Kk) {
  __shared__ __align__(16) short sA[3 * 128 * 64];   // 48 KB
  __shared__ __align__(16) short sB[3 * 256 * 64];   // 96 KB
  gemm8_body<MODE>(A, Bt, bias, resid, outp, Nn, Kk, 1.0f,
                   blockIdx.x * 128, blockIdx.y * 256, sA, sB);
}

// ---------------- 256x256-tile 8-wave GEMM (r13-verified): BK=64, 2-buffer LDS ------
template <int MODE>
DEV void gemm2_body(const short* __restrict__ A, const short* __restrict__ Bt,
                    const float* __restrict__ bias, const float* __restrict__ resid,
                    void* __restrict__ outp, int Nn, int Kk, float scale,
                    int m0, int n0, short* __restrict__ sA, short* __restrict__ sB) {
  constexpr int TO = 256 * 64;   // shorts per tile buffer (A or B)
  const int tid = threadIdx.x;
  const int wave = tid >> 6, lane = tid & 63, quad = lane >> 4, l15 = lane & 15;
  const int wm = (wave >> 2) * 128, wn = (wave & 3) * 64;

  const int sr = tid >> 3, su = tid & 7;
  const int sx = (su ^ (sr & 7)) * 8;                 // (row&7) invariant under +64
  const short* gA0 = A + (size_t)(m0 + sr) * Kk + sx;
  const short* gB0 = Bt + (size_t)(n0 + sr) * Kk + sx;

  const f32x4 fzero = {0.f, 0.f, 0.f, 0.f};
  f32x4 acc[8][4];
  #pragma unroll
  for (int mi = 0; mi < 8; mi++)
    #pragma unroll
    for (int ni = 0; ni < 4; ni++) acc[mi][ni] = fzero;

  const int nkt = Kk >> 6;

  auto stgPair = [&](int t, int p) {
    const int b_ = t & 1, ko = t << 6;
    gload16(gA0 + (size_t)(p * 64) * Kk + ko,
            &sA[(size_t)b_ * TO + (size_t)p * 4096 + (size_t)tid * 8]);
    gload16(gB0 + (size_t)(p * 64) * Kk + ko,
            &sB[(size_t)b_ * TO + (size_t)p * 4096 + (size_t)tid * 8]);
  };

  #pragma unroll
  for (int p = 0; p < 4; p++) stgPair(0, p);

  for (int t = 0; t < nkt; t++) {
    asm volatile("s_waitcnt vmcnt(0)" ::: "memory");
    __builtin_amdgcn_s_barrier();
    const short* a_ = &sA[(size_t)(t & 1) * TO];
    const short* b_ = &sB[(size_t)(t & 1) * TO];
    short8 bv[4][2];   // B fragments: read once (phase 0), cached across phases 1-3
    #pragma unroll
    for (int ph = 0; ph < 4; ph++) {
      short8 av[2][2];
      #pragma unroll
      for (int m2 = 0; m2 < 2; m2++) {
        const int rA = wm + (ph * 2 + m2) * 16 + l15, sw = rA & 7;
        #pragma unroll
        for (int ks = 0; ks < 2; ks++)
          av[m2][ks] = *(const short8*)&a_[rA * 64 + ((ks * 4 + quad) ^ sw) * 8];
      }
      if (ph == 0) {
        #pragma unroll
        for (int n2 = 0; n2 < 4; n2++) {
          const int rB = wn + n2 * 16 + l15, sw = rB & 7;
          #pragma unroll
          for (int ks = 0; ks < 2; ks++)
            bv[n2][ks] = *(const short8*)&b_[rB * 64 + ((ks * 4 + quad) ^ sw) * 8];
        }
      }
      if (t + 1 < nkt) stgPair(t + 1, ph);
      __builtin_amdgcn_s_barrier();
      asm volatile("s_waitcnt lgkmcnt(0)" ::: "memory");
      __builtin_amdgcn_sched_barrier(0);
      __builtin_amdgcn_s_setprio(1);
      #pragma unroll
      for (int ks = 0; ks < 2; ks++)
        #pragma unroll
        for (int m2 = 0; m2 < 2; m2++)
          #pragma unroll
          for (int n2 = 0; n2 < 4; n2++)
            acc[ph * 2 + m2][n2] = __builtin_amdgcn_mfma_f32_16x16x32_bf16(
                av[m2][ks], bv[n2][ks], acc[ph * 2 + m2][n2], 0, 0, 0);
      __builtin_amdgcn_s_setprio(0);
      __builtin_amdgcn_s_barrier();
    }
  }

  float bb[4];
  #pragma unroll
  for (int ni = 0; ni < 4; ni++) bb[ni] = bias[n0 + wn + ni * 16 + l15];
  #pragma unroll
  for (int mi = 0; mi < 8; mi++) {
    #pragma unroll
    for (int ni = 0; ni < 4; ni++) {
      #pragma unroll
      for (int r = 0; r < 4; r++) {
        int row = m0 + wm + mi * 16 + quad * 4 + r;
        int col = n0 + wn + ni * 16 + l15;
        float v = (acc[mi][ni][r] + bb[ni]) * scale;
        if constexpr (MODE == 1) v = v >= 0.f ? v : 0.1f * v;
        if constexpr (MODE == 2)
          ((float*)outp)[(size_t)row * Nn + col] = resid[(size_t)row * Nn + col] + v;
        else
          ((short*)outp)[(size_t)row * Nn + col] = f2bf(v);
      }
    }
  }
}

template <int MODE>
__global__ __launch_bounds__(512, 1)
void k_gemm2(const short* __restrict__ A, const short* __restrict__ Bt,
             const float* __restrict__ bias, const float* __restrict__ resid,
             void* __restrict__ outp, int Nn, int Kk) {
  __shared__ __align__(16) short sA[2 * 256 * 64];   // 64 KB
  __shared__ __align__(16) short sB[2 * 256 * 64];   // 64 KB
  gemm2_body<MODE>(A, Bt, bias, resid, outp, Nn, Kk, 1.0f,
                   blockIdx.x * 256, blockIdx.y * 256, sA, sB);
}

// fused QKV projection on the gemm2 structure: z selects {xq->Qm (scaled), xk->Km, xv->Vm}
__global__ __launch_bounds__(512, 1)
void k_gemm2_qkv(const short* __restrict__ xq, const short* __restrict__ xk,
                 const short* __restrict__ xv,
                 const short* __restrict__ wqT, const short* __restrict__ wkT,
                 const short* __restrict__ wvT,
                 const float* __restrict__ bq, const float* __restrict__ bk,
                 const float* __restrict__ bv,
                 short* __restrict__ Qm, short* __restrict__ Km, short* __restrict__ Vm) {
  __shared__ __align__(16) short sA[2 * 256 * 64];
  __shared__ __align__(16) short sB[2 * 256 * 64];
  const int z = blockIdx.z;
  const short* A    = z == 0 ? xq : z == 1 ? xk : xv;
  const short* Bt   = z == 0 ? wqT : z == 1 ? wkT : wvT;
  const float* bias = z == 0 ? bq : z == 1 ? bk : bv;
  short* outp       = z == 0 ? Qm : z == 1 ? Km : Vm;
  const float scale = z == 0 ? 0.1803368801111244f : 1.0f;   // 0.125 * log2(e) on Q
  gemm2_body<0>(A, Bt, bias, nullptr, outp, C, C, scale,
                blockIdx.x * 256, blockIdx.y * 256, sA, sB);
}

// ---------------- flash attention, S^T formulation (4-wave, r14-best) ----------------
// r17: reverted from 8-wave (r17 measured: 2x LDS traffic -> 2x conflicts -> 94->106us).
// V-read conflict fix: ALL 8.4M conflicts were the PV b64 reads (K b128 path = 0, as in
// GEMM). Read the full 16B slot as b128 (quad pairs broadcast the same address) and
// register-select the 8B half by quad&1 — same bytes, conflict-free pattern.
__global__ __launch_bounds__(256, 4)
void k_attn(const short* __restrict__ Q, const short* __restrict__ K,
            const short* __restrict__ Vt, short* __restrict__ O) {
  __shared__ __align__(16) short sK[2][64 * 64];
  __shared__ __align__(16) short sV[2][64 * 64];   // Vt tile: [d][key]
  const int tid = threadIdx.x;
  const int bh = blockIdx.x;                        // bh fastest -> XCD-pinned K/V reuse
  const int b = bh >> 4, h = bh & 15;
  const int q0 = blockIdx.y * 128;
  const int wave = tid >> 6, lane = tid & 63, quad = lane >> 4, l15 = lane & 15;
  const int wm = wave * 32;        // 32 q-rows per wave
  const size_t tokBase = (size_t)b * SEQ;

  // Q fragments in registers (B-operand of QK^T): [qi][d-half]
  short8 qf[2][2];
  #pragma unroll
  for (int qi = 0; qi < 2; qi++)
    #pragma unroll
    for (int hf = 0; hf < 2; hf++)
      qf[qi][hf] = *(const short8*)(Q + (tokBase + q0 + wm + qi * 16 + l15) * C
                                    + h * HD + hf * 32 + quad * 8);

  const int r0 = tid >> 3,        c0s = ((tid & 7) ^ (r0 & 7)) * 8;
  const int r1 = (tid + 256) >> 3, c1s = ((tid & 7) ^ (r1 & 7)) * 8;
  const short* gK0 = K + (tokBase + r0) * C + h * HD + c0s;
  const short* gK1 = K + (tokBase + r1) * C + h * HD + c1s;
  const short* gV0 = Vt + ((size_t)bh * HD + r0) * SEQ + c0s;
  const short* gV1 = Vt + ((size_t)bh * HD + r1) * SEQ + c1s;
  short* lK0 = &sK[0][tid * 8];
  short* lK1 = &sK[0][(tid + 256) * 8];
  short* lV0 = &sV[0][tid * 8];
  short* lV1 = &sV[0][(tid + 256) * 8];
  constexpr int BUFO = 64 * 64;   // shorts per buffer

#define STAGE(bufsel, kb) {                                   \
    int kk = (kb) * 64, bo = (bufsel) * BUFO;                 \
    gload16(gK0 + (size_t)kk * C, lK0 + bo);                  \
    gload16(gK1 + (size_t)kk * C, lK1 + bo);                  \
    gload16(gV0 + kk,             lV0 + bo);                  \
    gload16(gV1 + kk,             lV1 + bo); }

  const f32x4 fzero = {0.f, 0.f, 0.f, 0.f};
  const short4v onesv = {0x3F80, 0x3F80, 0x3F80, 0x3F80};   // bf16 1.0 x4
  f32x4 o[2][4];
  f32x4 oSum[2] = {fzero, fzero};
  #pragma unroll
  for (int qi = 0; qi < 2; qi++)
    #pragma unroll
    for (int di = 0; di < 4; di++) o[qi][di] = fzero;

  const int sw = l15 & 7;                    // seg swizzle key
  const int ql = quad & 1;                   // 8B half selector for PV reads

  STAGE(0, 0)

  for (int kb = 0; kb < SEQ / 64; kb++) {
    const int buf = kb & 1;
    __syncthreads();
    if (kb + 1 < SEQ / 64) STAGE(buf ^ 1, kb + 1)

    unsigned pk[4][2][2];
    #pragma unroll
    for (int ki = 0; ki < 4; ki++) {
      const int krow = (ki * 16 + l15) * 64;
      short8 a0 = *(const short8*)&sK[buf][krow + ((0 + quad) ^ sw) * 8];
      short8 a1 = *(const short8*)&sK[buf][krow + ((4 + quad) ^ sw) * 8];
      #pragma unroll
      for (int qi = 0; qi < 2; qi++) {
        f32x4 st = __builtin_amdgcn_mfma_f32_16x16x32_bf16(a0, qf[qi][0], fzero, 0, 0, 0);
        st = __builtin_amdgcn_mfma_f32_16x16x32_bf16(a1, qf[qi][1], st, 0, 0, 0);
        float p0 = fexp2(st[0]), p1 = fexp2(st[1]);
        float p2 = fexp2(st[2]), p3 = fexp2(st[3]);
        pk[ki][qi][0] = packrn(p0, p1);
        pk[ki][qi][1] = packrn(p2, p3);
      }
    }

    #pragma unroll
    for (int ki = 0; ki < 4; ki++) {
      short4v bv[4];
      const int g16 = ((ki * 2 + (quad >> 1)) ^ sw) * 8;   // 16B slot (both 8B halves)
      #pragma unroll
      for (int di = 0; di < 4; di++) {
        short8 w = *(const short8*)&sV[buf][(di * 16 + l15) * 64 + g16];
        short4v lo = {w[0], w[1], w[2], w[3]};
        short4v hi = {w[4], w[5], w[6], w[7]};
        bv[di] = ql ? hi : lo;
      }
      #pragma unroll
      for (int qi = 0; qi < 2; qi++) {
        int2v t; t.x = (int)pk[ki][qi][0]; t.y = (int)pk[ki][qi][1];
        short4v aP = __builtin_bit_cast(short4v, t);
        oSum[qi] = mfma16(aP, onesv, oSum[qi]);
        #pragma unroll
        for (int di = 0; di < 4; di++)
          o[qi][di] = mfma16(aP, bv[di], o[qi][di]);
      }
    }
  }
#undef STAGE

  float linv[2][4];
  #pragma unroll
  for (int qi = 0; qi < 2; qi++)
    #pragma unroll
    for (int r = 0; r < 4; r++)
      linv[qi][r] = 1.0f / oSum[qi][r];

  #pragma unroll
  for (int qi = 0; qi < 2; qi++)
    #pragma unroll
    for (int di = 0; di < 4; di++)
      #pragma unroll
      for (int r = 0; r < 4; r++) {
        int row = q0 + wm + qi * 16 + quad * 4 + r;
        int col = h * HD + di * 16 + l15;
        O[(tokBase + row) * C + col] = f2bf(o[qi][di][r] * linv[qi][r]);
      }
}

extern "C" void kernel_launch(void* const* d_in, const int* in_sizes, int n_in,
                              void* d_out, int out_size, void* d_ws, size_t ws_size,
                              hipStream_t stream) {
  const float* x   = (const float*)d_in[0];
  const float* pos = (const float*)d_in[1];
  const float* nqg = (const float*)d_in[2];
  const float* nqb = (const float*)d_in[3];
  const float* nkg = (const float*)d_in[4];
  const float* nkb = (const float*)d_in[5];
  const float* nvg = (const float*)d_in[6];
  const float* nvb = (const float*)d_in[7];
  const float* ng  = (const float*)d_in[8];
  const float* nb  = (const float*)d_in[9];
  const float* wq  = (const float*)d_in[10];
  const float* bq  = (const float*)d_in[11];
  const float* wk  = (const float*)d_in[12];
  const float* bk  = (const float*)d_in[13];
  const float* wv  = (const float*)d_in[14];
  const float* bv  = (const float*)d_in[15];
  const float* wp  = (const float*)d_in[16];
  const float* bp  = (const float*)d_in[17];
  const float* w1  = (const float*)d_in[18];
  const float* b1  = (const float*)d_in[19];
  const float* w2  = (const float*)d_in[20];
  const float* b2  = (const float*)d_in[21];

  char* ws = (char*)d_ws;
  const size_t MB = 1u << 20;
  short* wqT  = (short*)(ws + 0 * MB);
  short* wkT  = (short*)(ws + 2 * MB);
  short* wvT  = (short*)(ws + 4 * MB);
  short* wpT  = (short*)(ws + 6 * MB);
  short* w1T  = (short*)(ws + 8 * MB);     // [HID][C]
  short* w2T  = (short*)(ws + 16 * MB);    // [C][HID]
  short* xq   = (short*)(ws + 24 * MB);
  short* xk   = (short*)(ws + 40 * MB);
  short* xv   = (short*)(ws + 56 * MB);
  short* Qm   = (short*)(ws + 72 * MB);
  short* Km   = (short*)(ws + 88 * MB);
  short* Vm   = (short*)(ws + 104 * MB);
  short* Vt   = (short*)(ws + 120 * MB);
  short* y1   = (short*)(ws + 72 * MB);    // overlays Q/K/V/Vt (dead after attn)
  short* Ob   = xk;                         // overlays xk (dead after K-proj)
  short* hln  = xq;                         // overlays xq (dead after Q-proj)
  float* hbuf = (float*)(ws + 136 * MB);
  (void)ws_size; (void)in_sizes; (void)n_in; (void)out_size;

  dim3 blk(256);
  k_transpose_w4<<<dim3(32, 32, 4), blk, 0, stream>>>(wq, wk, wv, wp, wqT, wkT, wvT, wpT);
  k_transpose_w<<<dim3(128, 32), blk, 0, stream>>>(w1, w1T, C, HID);
  k_transpose_w<<<dim3(32, 128), blk, 0, stream>>>(w2, w2T, HID, C);
  k_ln_qkv<<<dim3(MTOT), blk, 0, stream>>>(x, pos, nqg, nqb, nkg, nkb, nvg, nvb, xq, xk, xv);
  // QKV: gemm2 (z-stack gives 384 blocks; 2x-work tiles -> effective 3 work-rounds).
  k_gemm2_qkv<<<dim3(MTOT / 256, C / 256, 3), dim3(512), 0, stream>>>(
      xq, xk, xv, wqT, wkT, wvT, bq, bk, bv, Qm, Km, Vm);
  k_transpose_v<<<dim3(SEQ / 32, HD / 32, Bb * NH), blk, 0, stream>>>(Vm, Vt);
  // attn: 4-wave blocks (r14-best) + conflict-free b128 V reads.
  k_attn<<<dim3(Bb * NH, SEQ / 128), blk, 0, stream>>>(Qm, Km, Vt, Ob);
  // wp (N=1024): gemm8 — 256 blocks = 1/CU (gemm2 would starve at 128).
  k_gemm8<2><<<dim3(MTOT / 128, C / 256), dim3(512), 0, stream>>>(Ob, wpT, bp, x, hbuf, C, C);
  k_ln1<<<dim3(MTOT), blk, 0, stream>>>(hbuf, ng, nb, hln);
  // MLP1 (N=4096): gemm2 — 512 blocks = 2 full rounds of 2x-efficient tiles.
  k_gemm2<1><<<dim3(MTOT / 256, HID / 256), dim3(512), 0, stream>>>(hln, w1T, b1, nullptr,
                                                                    y1, HID, C);
  // MLP2 (N=1024): gemm8 — 256 blocks = 1/CU.
  k_gemm8<2><<<dim3(MTOT / 128, C / 256), dim3(512), 0, stream>>>(y1, w2T, b2, hbuf,
                                                                  (float*)d_out, C, HID);
}

// Round 20
// 516.236 us; speedup vs baseline: 1.0517x; 1.0265x over previous
//
#include <hip/hip_runtime.h>
#include <hip/hip_bf16.h>

#define DEV __device__ __forceinline__

typedef __attribute__((ext_vector_type(8))) short short8;
typedef __attribute__((ext_vector_type(4))) short short4v;
typedef __attribute__((ext_vector_type(4))) float f32x4;
typedef __attribute__((ext_vector_type(2))) int int2v;

constexpr int Bb   = 4;
constexpr int SEQ  = 2048;
constexpr int C    = 1024;
constexpr int HID  = 4096;
constexpr int NH   = 16;
constexpr int HD   = 64;
constexpr int MTOT = Bb * SEQ;   // 8192 tokens

DEV unsigned bfbits(float f) {
  unsigned x = __float_as_uint(f);
  return (x + 0x7fffu + ((x >> 16) & 1u)) >> 16;   // RNE to bf16, low 16 bits
}

DEV short f2bf(float f) { return (short)bfbits(f); }

// fast bf16 pair pack: +0x8000 (round-half-up, inputs positive finite) + byte perm
DEV unsigned packrn(float a, float b) {
  unsigned ua = __float_as_uint(a) + 0x8000u;
  unsigned ub = __float_as_uint(b) + 0x8000u;
  return __builtin_amdgcn_perm(ub, ua, 0x07060302u);
}

// raw v_exp_f32 (2^x), no OCML denorm guard (flush-to-zero fine for softmax)
DEV float fexp2(float x) {
#if __has_builtin(__builtin_amdgcn_exp2f)
  return __builtin_amdgcn_exp2f(x);
#else
  float r;
  asm("v_exp_f32 %0, %1" : "=v"(r) : "v"(x));
  return r;
#endif
}

DEV void gload16(const void* g, void* l) {
  __builtin_amdgcn_global_load_lds((const __attribute__((address_space(1))) void*)g,
                                   (__attribute__((address_space(3))) void*)l, 16, 0, 0);
}

// 16x16x16 bf16 MFMA (A/B = 2 VGPRs = 4 bf16)
DEV f32x4 mfma16(short4v a, short4v b, f32x4 c) {
#if __has_builtin(__builtin_amdgcn_mfma_f32_16x16x16bf16_1k)
  return __builtin_amdgcn_mfma_f32_16x16x16bf16_1k(a, b, c, 0, 0, 0);
#else
  asm volatile("v_mfma_f32_16x16x16_bf16 %0, %1, %2, %0" : "+v"(c) : "v"(a), "v"(b));
  return c;
#endif
}

// ---------------- weight transpose: fp32 [R][Cc] -> bf16 [Cc][R] ----------------
DEV void transpose_body(const float* __restrict__ src, short* __restrict__ dst,
                        int R, int Cc) {
  __shared__ float t[32][33];
  int tx = threadIdx.x & 31, ty = threadIdx.x >> 5;   // 32 x 8
  int c0 = blockIdx.x * 32, r0 = blockIdx.y * 32;
  #pragma unroll
  for (int i = 0; i < 4; i++)
    t[ty + i * 8][tx] = src[(size_t)(r0 + ty + i * 8) * Cc + c0 + tx];
  __syncthreads();
  #pragma unroll
  for (int i = 0; i < 4; i++)
    dst[(size_t)(c0 + ty + i * 8) * R + r0 + tx] = f2bf(t[tx][ty + i * 8]);
}

__global__ void k_transpose_w(const float* __restrict__ src, short* __restrict__ dst,
                              int R, int Cc) {
  transpose_body(src, dst, R, Cc);
}

// 4 square CxC transposes in one launch (z selects)
__global__ void k_transpose_w4(const float* __restrict__ s0, const float* __restrict__ s1,
                               const float* __restrict__ s2, const float* __restrict__ s3,
                               short* __restrict__ d0, short* __restrict__ d1,
                               short* __restrict__ d2, short* __restrict__ d3) {
  const float* s = blockIdx.z == 0 ? s0 : blockIdx.z == 1 ? s1 : blockIdx.z == 2 ? s2 : s3;
  short*       d = blockIdx.z == 0 ? d0 : blockIdx.z == 1 ? d1 : blockIdx.z == 2 ? d2 : d3;
  transpose_body(s, d, C, C);
}

// ---------------- V transpose: bf16 [tok][C] -> per-(b,h) [HD][SEQ] ----------------
__global__ void k_transpose_v(const short* __restrict__ V, short* __restrict__ Vt) {
  __shared__ short t[32][33];
  int tx = threadIdx.x & 31, ty = threadIdx.x >> 5;
  int plane = blockIdx.z;                 // b*16 + h
  int b = plane >> 4, h = plane & 15;
  int n0 = blockIdx.x * 32, d0 = blockIdx.y * 32;
  #pragma unroll
  for (int i = 0; i < 4; i++)
    t[ty + i * 8][tx] = V[(size_t)(b * SEQ + n0 + ty + i * 8) * C + h * HD + d0 + tx];
  __syncthreads();
  #pragma unroll
  for (int i = 0; i < 4; i++)
    Vt[((size_t)plane * HD + d0 + ty + i * 8) * SEQ + n0 + tx] = t[tx][ty + i * 8];
}

// ---------------- fused LN for q-input (x) and kv-input (x+pos) ----------------
__global__ void k_ln_qkv(const float* __restrict__ x, const float* __restrict__ pos,
                         const float* __restrict__ nqg, const float* __restrict__ nqb,
                         const float* __restrict__ nkg, const float* __restrict__ nkb,
                         const float* __restrict__ nvg, const float* __restrict__ nvb,
                         short* __restrict__ xq, short* __restrict__ xk,
                         short* __restrict__ xv) {
  int row = blockIdx.x, tid = threadIdx.x;
  int n = row & (SEQ - 1);
  float a4[4], p4[4];
  float s1 = 0, s2 = 0, t1 = 0, t2 = 0;
  #pragma unroll
  for (int i = 0; i < 4; i++) {
    int c = tid + i * 256;
    float a = x[(size_t)row * C + c];
    float p = pos[(size_t)n * C + c] + a;
    a4[i] = a; p4[i] = p;
    s1 += a; s2 += a * a; t1 += p; t2 += p * p;
  }
  #pragma unroll
  for (int off = 32; off; off >>= 1) {
    s1 += __shfl_xor(s1, off, 64);
    s2 += __shfl_xor(s2, off, 64);
    t1 += __shfl_xor(t1, off, 64);
    t2 += __shfl_xor(t2, off, 64);
  }
  __shared__ float red[4][4];
  int wave = tid >> 6, lane = tid & 63;
  if (lane == 0) { red[wave][0] = s1; red[wave][1] = s2; red[wave][2] = t1; red[wave][3] = t2; }
  __syncthreads();
  s1 = red[0][0] + red[1][0] + red[2][0] + red[3][0];
  s2 = red[0][1] + red[1][1] + red[2][1] + red[3][1];
  t1 = red[0][2] + red[1][2] + red[2][2] + red[3][2];
  t2 = red[0][3] + red[1][3] + red[2][3] + red[3][3];
  float mq = s1 * (1.f / C), mk = t1 * (1.f / C);
  float rq = rsqrtf(s2 * (1.f / C) - mq * mq + 1e-5f);
  float rk = rsqrtf(t2 * (1.f / C) - mk * mk + 1e-5f);
  #pragma unroll
  for (int i = 0; i < 4; i++) {
    int c = tid + i * 256;
    float nq_ = (a4[i] - mq) * rq;
    float nk_ = (p4[i] - mk) * rk;
    xq[(size_t)row * C + c] = f2bf(nq_ * nqg[c] + nqb[c]);
    xk[(size_t)row * C + c] = f2bf(nk_ * nkg[c] + nkb[c]);
    xv[(size_t)row * C + c] = f2bf(nk_ * nvg[c] + nvb[c]);
  }
}

// ---------------- plain LN (h -> bf16) ----------------
__global__ void k_ln1(const float* __restrict__ h, const float* __restrict__ g,
                      const float* __restrict__ bta, short* __restrict__ out) {
  int row = blockIdx.x, tid = threadIdx.x;
  float a4[4];
  float s1 = 0, s2 = 0;
  #pragma unroll
  for (int i = 0; i < 4; i++) {
    int c = tid + i * 256;
    float a = h[(size_t)row * C + c];
    a4[i] = a; s1 += a; s2 += a * a;
  }
  #pragma unroll
  for (int off = 32; off; off >>= 1) {
    s1 += __shfl_xor(s1, off, 64);
    s2 += __shfl_xor(s2, off, 64);
  }
  __shared__ float red[4][2];
  int wave = tid >> 6, lane = tid & 63;
  if (lane == 0) { red[wave][0] = s1; red[wave][1] = s2; }
  __syncthreads();
  s1 = red[0][0] + red[1][0] + red[2][0] + red[3][0];
  s2 = red[0][1] + red[1][1] + red[2][1] + red[3][1];
  float m = s1 * (1.f / C);
  float r = rsqrtf(s2 * (1.f / C) - m * m + 1e-5f);
  #pragma unroll
  for (int i = 0; i < 4; i++) {
    int c = tid + i * 256;
    out[(size_t)row * C + c] = f2bf((a4[i] - m) * r * g[c] + bta[c]);
  }
}

// ---------------- 8-wave pipelined GEMM body: BM=128 BN=256 BK=64, 3-buffer LDS ------
template <int MODE>
DEV void gemm8_body(const short* __restrict__ A, const short* __restrict__ Bt,
                    const float* __restrict__ bias, const float* __restrict__ resid,
                    void* __restrict__ outp, int Nn, int Kk, float scale,
                    int m0, int n0, short* __restrict__ sA, short* __restrict__ sB) {
  constexpr int AO = 128 * 64, BO = 256 * 64;   // shorts per buffer
  const int tid = threadIdx.x;
  const int wave = tid >> 6, lane = tid & 63, quad = lane >> 4, l15 = lane & 15;
  const int wm = (wave >> 2) * 64, wn = (wave & 3) * 64;

  const int sr = tid >> 3, su = tid & 7;
  const int sx = (su ^ (sr & 7)) * 8;                 // (row&7) invariant under +64
  const short* gA0 = A + (size_t)(m0 + sr) * Kk + sx;
  const short* gA1 = gA0 + (size_t)64 * Kk;
  const short* gB0 = Bt + (size_t)(n0 + sr) * Kk + sx;
  const short* gB1 = gB0 + (size_t)64 * Kk;
  const short* gB2 = gB0 + (size_t)128 * Kk;
  const short* gB3 = gB0 + (size_t)192 * Kk;

  const f32x4 fzero = {0.f, 0.f, 0.f, 0.f};
  f32x4 acc[4][4];
  #pragma unroll
  for (int mi = 0; mi < 4; mi++)
    #pragma unroll
    for (int ni = 0; ni < 4; ni++) acc[mi][ni] = fzero;

  const int nkt = Kk >> 6;

  auto stg = [&](int t) {
    const int b_ = t % 3, ko = t << 6;
    gload16(gA0 + ko, &sA[(size_t)b_ * AO + (size_t)tid * 8]);
    gload16(gA1 + ko, &sA[(size_t)b_ * AO + (size_t)(512 + tid) * 8]);
    gload16(gB0 + ko, &sB[(size_t)b_ * BO + (size_t)tid * 8]);
    gload16(gB1 + ko, &sB[(size_t)b_ * BO + (size_t)(512 + tid) * 8]);
    gload16(gB2 + ko, &sB[(size_t)b_ * BO + (size_t)(1024 + tid) * 8]);
    gload16(gB3 + ko, &sB[(size_t)b_ * BO + (size_t)(1536 + tid) * 8]);
  };
  auto stgA_ = [&](int t) {
    const int b_ = t % 3, ko = t << 6;
    gload16(gA0 + ko, &sA[(size_t)b_ * AO + (size_t)tid * 8]);
    gload16(gA1 + ko, &sA[(size_t)b_ * AO + (size_t)(512 + tid) * 8]);
    gload16(gB0 + ko, &sB[(size_t)b_ * BO + (size_t)tid * 8]);
  };
  auto stgB_ = [&](int t) {
    const int b_ = t % 3, ko = t << 6;
    gload16(gB1 + ko, &sB[(size_t)b_ * BO + (size_t)(512 + tid) * 8]);
    gload16(gB2 + ko, &sB[(size_t)b_ * BO + (size_t)(1024 + tid) * 8]);
    gload16(gB3 + ko, &sB[(size_t)b_ * BO + (size_t)(1536 + tid) * 8]);
  };

  stg(0);
  if (nkt > 1) stg(1);

  for (int t = 0; t < nkt; t++) {
    if (t + 1 < nkt) asm volatile("s_waitcnt vmcnt(6)" ::: "memory");
    else             asm volatile("s_waitcnt vmcnt(0)" ::: "memory");
    __builtin_amdgcn_s_barrier();
    const short* a_ = &sA[(size_t)(t % 3) * AO];
    const short* b_ = &sB[(size_t)(t % 3) * BO];
    short8 av[4][2];   // A fragments: read once (phase 0), cached across phase 1
    {
      short8 bv[2][2];
      #pragma unroll
      for (int m2 = 0; m2 < 4; m2++) {
        const int rA = wm + m2 * 16 + l15, sw = rA & 7;
        #pragma unroll
        for (int ks = 0; ks < 2; ks++)
          av[m2][ks] = *(const short8*)&a_[rA * 64 + ((ks * 4 + quad) ^ sw) * 8];
      }
      #pragma unroll
      for (int n2 = 0; n2 < 2; n2++) {
        const int rB = wn + n2 * 16 + l15, sw = rB & 7;
        #pragma unroll
        for (int ks = 0; ks < 2; ks++)
          bv[n2][ks] = *(const short8*)&b_[rB * 64 + ((ks * 4 + quad) ^ sw) * 8];
      }
      if (t + 2 < nkt) stgA_(t + 2);
      __builtin_amdgcn_s_barrier();
      asm volatile("s_waitcnt lgkmcnt(0)" ::: "memory");
      __builtin_amdgcn_sched_barrier(0);
      __builtin_amdgcn_s_setprio(1);
      #pragma unroll
      for (int ks = 0; ks < 2; ks++)
        #pragma unroll
        for (int m2 = 0; m2 < 4; m2++)
          #pragma unroll
          for (int n2 = 0; n2 < 2; n2++)
            acc[m2][n2] = __builtin_amdgcn_mfma_f32_16x16x32_bf16(
                av[m2][ks], bv[n2][ks], acc[m2][n2], 0, 0, 0);
      __builtin_amdgcn_s_setprio(0);
      __builtin_amdgcn_s_barrier();
    }
    {
      short8 bv[2][2];
      #pragma unroll
      for (int n2 = 0; n2 < 2; n2++) {
        const int rB = wn + (2 + n2) * 16 + l15, sw = rB & 7;
        #pragma unroll
        for (int ks = 0; ks < 2; ks++)
          bv[n2][ks] = *(const short8*)&b_[rB * 64 + ((ks * 4 + quad) ^ sw) * 8];
      }
      if (t + 2 < nkt) stgB_(t + 2);
      __builtin_amdgcn_s_barrier();
      asm volatile("s_waitcnt lgkmcnt(0)" ::: "memory");
      __builtin_amdgcn_sched_barrier(0);
      __builtin_amdgcn_s_setprio(1);
      #pragma unroll
      for (int ks = 0; ks < 2; ks++)
        #pragma unroll
        for (int m2 = 0; m2 < 4; m2++)
          #pragma unroll
          for (int n2 = 0; n2 < 2; n2++)
            acc[m2][2 + n2] = __builtin_amdgcn_mfma_f32_16x16x32_bf16(
                av[m2][ks], bv[n2][ks], acc[m2][2 + n2], 0, 0, 0);
      __builtin_amdgcn_s_setprio(0);
      __builtin_amdgcn_s_barrier();
    }
  }

  float bb[4];
  #pragma unroll
  for (int ni = 0; ni < 4; ni++) bb[ni] = bias[n0 + wn + ni * 16 + l15];
  #pragma unroll
  for (int mi = 0; mi < 4; mi++) {
    #pragma unroll
    for (int ni = 0; ni < 4; ni++) {
      #pragma unroll
      for (int r = 0; r < 4; r++) {
        int row = m0 + wm + mi * 16 + quad * 4 + r;
        int col = n0 + wn + ni * 16 + l15;
        float v = (acc[mi][ni][r] + bb[ni]) * scale;
        if constexpr (MODE == 1) v = v >= 0.f ? v : 0.1f * v;
        if constexpr (MODE == 2)
          ((float*)outp)[(size_t)row * Nn + col] = resid[(size_t)row * Nn + col] + v;
        else
          ((short*)outp)[(size_t)row * Nn + col] = f2bf(v);
      }
    }
  }
}

template <int MODE>
__global__ __launch_bounds__(512, 1)
void k_gemm8(const short* __restrict__ A, const short* __restrict__ Bt,
             const float* __restrict__ bias, const float* __restrict__ resid,
             void* __restrict__ outp, int Nn, int Kk) {
  __shared__ __align__(16) short sA[3 * 128 * 64];   // 48 KB
  __shared__ __align__(16) short sB[3 * 256 * 64];   // 96 KB
  gemm8_body<MODE>(A, Bt, bias, resid, outp, Nn, Kk, 1.0f,
                   blockIdx.x * 128, blockIdx.y * 256, sA, sB);
}

// ---------------- 256x256-tile 8-wave GEMM (r13-verified): BK=64, 2-buffer LDS ------
template <int MODE>
DEV void gemm2_body(const short* __restrict__ A, const short* __restrict__ Bt,
                    const float* __restrict__ bias, const float* __restrict__ resid,
                    void* __restrict__ outp, int Nn, int Kk, float scale,
                    int m0, int n0, short* __restrict__ sA, short* __restrict__ sB) {
  constexpr int TO = 256 * 64;   // shorts per tile buffer (A or B)
  const int tid = threadIdx.x;
  const int wave = tid >> 6, lane = tid & 63, quad = lane >> 4, l15 = lane & 15;
  const int wm = (wave >> 2) * 128, wn = (wave & 3) * 64;

  const int sr = tid >> 3, su = tid & 7;
  const int sx = (su ^ (sr & 7)) * 8;                 // (row&7) invariant under +64
  const short* gA0 = A + (size_t)(m0 + sr) * Kk + sx;
  const short* gB0 = Bt + (size_t)(n0 + sr) * Kk + sx;

  const f32x4 fzero = {0.f, 0.f, 0.f, 0.f};
  f32x4 acc[8][4];
  #pragma unroll
  for (int mi = 0; mi < 8; mi++)
    #pragma unroll
    for (int ni = 0; ni < 4; ni++) acc[mi][ni] = fzero;

  const int nkt = Kk >> 6;

  auto stgPair = [&](int t, int p) {
    const int b_ = t & 1, ko = t << 6;
    gload16(gA0 + (size_t)(p * 64) * Kk + ko,
            &sA[(size_t)b_ * TO + (size_t)p * 4096 + (size_t)tid * 8]);
    gload16(gB0 + (size_t)(p * 64) * Kk + ko,
            &sB[(size_t)b_ * TO + (size_t)p * 4096 + (size_t)tid * 8]);
  };

  #pragma unroll
  for (int p = 0; p < 4; p++) stgPair(0, p);

  for (int t = 0; t < nkt; t++) {
    asm volatile("s_waitcnt vmcnt(0)" ::: "memory");
    __builtin_amdgcn_s_barrier();
    const short* a_ = &sA[(size_t)(t & 1) * TO];
    const short* b_ = &sB[(size_t)(t & 1) * TO];
    short8 bv[4][2];   // B fragments: read once (phase 0), cached across phases 1-3
    #pragma unroll
    for (int ph = 0; ph < 4; ph++) {
      short8 av[2][2];
      #pragma unroll
      for (int m2 = 0; m2 < 2; m2++) {
        const int rA = wm + (ph * 2 + m2) * 16 + l15, sw = rA & 7;
        #pragma unroll
        for (int ks = 0; ks < 2; ks++)
          av[m2][ks] = *(const short8*)&a_[rA * 64 + ((ks * 4 + quad) ^ sw) * 8];
      }
      if (ph == 0) {
        #pragma unroll
        for (int n2 = 0; n2 < 4; n2++) {
          const int rB = wn + n2 * 16 + l15, sw = rB & 7;
          #pragma unroll
          for (int ks = 0; ks < 2; ks++)
            bv[n2][ks] = *(const short8*)&b_[rB * 64 + ((ks * 4 + quad) ^ sw) * 8];
        }
      }
      if (t + 1 < nkt) stgPair(t + 1, ph);
      __builtin_amdgcn_s_barrier();
      asm volatile("s_waitcnt lgkmcnt(0)" ::: "memory");
      __builtin_amdgcn_sched_barrier(0);
      __builtin_amdgcn_s_setprio(1);
      #pragma unroll
      for (int ks = 0; ks < 2; ks++)
        #pragma unroll
        for (int m2 = 0; m2 < 2; m2++)
          #pragma unroll
          for (int n2 = 0; n2 < 4; n2++)
            acc[ph * 2 + m2][n2] = __builtin_amdgcn_mfma_f32_16x16x32_bf16(
                av[m2][ks], bv[n2][ks], acc[ph * 2 + m2][n2], 0, 0, 0);
      __builtin_amdgcn_s_setprio(0);
      __builtin_amdgcn_s_barrier();
    }
  }

  float bb[4];
  #pragma unroll
  for (int ni = 0; ni < 4; ni++) bb[ni] = bias[n0 + wn + ni * 16 + l15];
  #pragma unroll
  for (int mi = 0; mi < 8; mi++) {
    #pragma unroll
    for (int ni = 0; ni < 4; ni++) {
      #pragma unroll
      for (int r = 0; r < 4; r++) {
        int row = m0 + wm + mi * 16 + quad * 4 + r;
        int col = n0 + wn + ni * 16 + l15;
        float v = (acc[mi][ni][r] + bb[ni]) * scale;
        if constexpr (MODE == 1) v = v >= 0.f ? v : 0.1f * v;
        if constexpr (MODE == 2)
          ((float*)outp)[(size_t)row * Nn + col] = resid[(size_t)row * Nn + col] + v;
        else
          ((short*)outp)[(size_t)row * Nn + col] = f2bf(v);
      }
    }
  }
}

template <int MODE>
__global__ __launch_bounds__(512, 1)
void k_gemm2(const short* __restrict__ A, const short* __restrict__ Bt,
             const float* __restrict__ bias, const float* __restrict__ resid,
             void* __restrict__ outp, int Nn, int Kk) {
  __shared__ __align__(16) short sA[2 * 256 * 64];   // 64 KB
  __shared__ __align__(16) short sB[2 * 256 * 64];   // 64 KB
  gemm2_body<MODE>(A, Bt, bias, resid, outp, Nn, Kk, 1.0f,
                   blockIdx.x * 256, blockIdx.y * 256, sA, sB);
}

// fused QKV projection on the gemm2 structure: z selects {xq->Qm (scaled), xk->Km, xv->Vm}
__global__ __launch_bounds__(512, 1)
void k_gemm2_qkv(const short* __restrict__ xq, const short* __restrict__ xk,
                 const short* __restrict__ xv,
                 const short* __restrict__ wqT, const short* __restrict__ wkT,
                 const short* __restrict__ wvT,
                 const float* __restrict__ bq, const float* __restrict__ bk,
                 const float* __restrict__ bv,
                 short* __restrict__ Qm, short* __restrict__ Km, short* __restrict__ Vm) {
  __shared__ __align__(16) short sA[2 * 256 * 64];
  __shared__ __align__(16) short sB[2 * 256 * 64];
  const int z = blockIdx.z;
  const short* A    = z == 0 ? xq : z == 1 ? xk : xv;
  const short* Bt   = z == 0 ? wqT : z == 1 ? wkT : wvT;
  const float* bias = z == 0 ? bq : z == 1 ? bk : bv;
  short* outp       = z == 0 ? Qm : z == 1 ? Km : Vm;
  const float scale = z == 0 ? 0.1803368801111244f : 1.0f;   // 0.125 * log2(e) on Q
  gemm2_body<0>(A, Bt, bias, nullptr, outp, C, C, scale,
                blockIdx.x * 256, blockIdx.y * 256, sA, sB);
}

// ---------------- flash attention, S^T formulation (r14-exact: session best) ----------------
// r17 (8-wave) and r18 (b128 V reads) both regressed; the 8.4M conflict reading is a
// saturated/quantized counter (exact 2^23 across unrelated kernels), not a real signal.
__global__ __launch_bounds__(256, 4)
void k_attn(const short* __restrict__ Q, const short* __restrict__ K,
            const short* __restrict__ Vt, short* __restrict__ O) {
  __shared__ __align__(16) short sK[2][64 * 64];
  __shared__ __align__(16) short sV[2][64 * 64];   // Vt tile: [d][key]
  const int tid = threadIdx.x;
  const int bh = blockIdx.x;                        // bh fastest -> XCD-pinned K/V reuse
  const int b = bh >> 4, h = bh & 15;
  const int q0 = blockIdx.y * 128;
  const int wave = tid >> 6, lane = tid & 63, quad = lane >> 4, l15 = lane & 15;
  const int wm = wave * 32;        // 32 q-rows per wave
  const size_t tokBase = (size_t)b * SEQ;

  // Q fragments in registers (B-operand of QK^T): [qi][d-half]
  short8 qf[2][2];
  #pragma unroll
  for (int qi = 0; qi < 2; qi++)
    #pragma unroll
    for (int hf = 0; hf < 2; hf++)
      qf[qi][hf] = *(const short8*)(Q + (tokBase + q0 + wm + qi * 16 + l15) * C
                                    + h * HD + hf * 32 + quad * 8);

  const int r0 = tid >> 3,        c0s = ((tid & 7) ^ (r0 & 7)) * 8;
  const int r1 = (tid + 256) >> 3, c1s = ((tid & 7) ^ (r1 & 7)) * 8;
  const short* gK0 = K + (tokBase + r0) * C + h * HD + c0s;
  const short* gK1 = K + (tokBase + r1) * C + h * HD + c1s;
  const short* gV0 = Vt + ((size_t)bh * HD + r0) * SEQ + c0s;
  const short* gV1 = Vt + ((size_t)bh * HD + r1) * SEQ + c1s;
  short* lK0 = &sK[0][tid * 8];
  short* lK1 = &sK[0][(tid + 256) * 8];
  short* lV0 = &sV[0][tid * 8];
  short* lV1 = &sV[0][(tid + 256) * 8];
  constexpr int BUFO = 64 * 64;   // shorts per buffer

#define STAGE(bufsel, kb) {                                   \
    int kk = (kb) * 64, bo = (bufsel) * BUFO;                 \
    gload16(gK0 + (size_t)kk * C, lK0 + bo);                  \
    gload16(gK1 + (size_t)kk * C, lK1 + bo);                  \
    gload16(gV0 + kk,             lV0 + bo);                  \
    gload16(gV1 + kk,             lV1 + bo); }

  const f32x4 fzero = {0.f, 0.f, 0.f, 0.f};
  const short4v onesv = {0x3F80, 0x3F80, 0x3F80, 0x3F80};   // bf16 1.0 x4
  f32x4 o[2][4];
  f32x4 oSum[2] = {fzero, fzero};
  #pragma unroll
  for (int qi = 0; qi < 2; qi++)
    #pragma unroll
    for (int di = 0; di < 4; di++) o[qi][di] = fzero;

  const int sw = l15 & 7;                    // seg swizzle key

  STAGE(0, 0)

  for (int kb = 0; kb < SEQ / 64; kb++) {
    const int buf = kb & 1;
    __syncthreads();
    if (kb + 1 < SEQ / 64) STAGE(buf ^ 1, kb + 1)

    unsigned pk[4][2][2];
    #pragma unroll
    for (int ki = 0; ki < 4; ki++) {
      const int krow = (ki * 16 + l15) * 64;
      short8 a0 = *(const short8*)&sK[buf][krow + ((0 + quad) ^ sw) * 8];
      short8 a1 = *(const short8*)&sK[buf][krow + ((4 + quad) ^ sw) * 8];
      #pragma unroll
      for (int qi = 0; qi < 2; qi++) {
        f32x4 st = __builtin_amdgcn_mfma_f32_16x16x32_bf16(a0, qf[qi][0], fzero, 0, 0, 0);
        st = __builtin_amdgcn_mfma_f32_16x16x32_bf16(a1, qf[qi][1], st, 0, 0, 0);
        float p0 = fexp2(st[0]), p1 = fexp2(st[1]);
        float p2 = fexp2(st[2]), p3 = fexp2(st[3]);
        pk[ki][qi][0] = packrn(p0, p1);
        pk[ki][qi][1] = packrn(p2, p3);
      }
    }

    #pragma unroll
    for (int ki = 0; ki < 4; ki++) {
      short4v bv[4];
      const int g = ((ki * 2 + (quad >> 1)) ^ sw) * 8 + (quad & 1) * 4;
      #pragma unroll
      for (int di = 0; di < 4; di++)
        bv[di] = *(const short4v*)&sV[buf][(di * 16 + l15) * 64 + g];
      #pragma unroll
      for (int qi = 0; qi < 2; qi++) {
        int2v t; t.x = (int)pk[ki][qi][0]; t.y = (int)pk[ki][qi][1];
        short4v aP = __builtin_bit_cast(short4v, t);
        oSum[qi] = mfma16(aP, onesv, oSum[qi]);
        #pragma unroll
        for (int di = 0; di < 4; di++)
          o[qi][di] = mfma16(aP, bv[di], o[qi][di]);
      }
    }
  }
#undef STAGE

  float linv[2][4];
  #pragma unroll
  for (int qi = 0; qi < 2; qi++)
    #pragma unroll
    for (int r = 0; r < 4; r++)
      linv[qi][r] = 1.0f / oSum[qi][r];

  #pragma unroll
  for (int qi = 0; qi < 2; qi++)
    #pragma unroll
    for (int di = 0; di < 4; di++)
      #pragma unroll
      for (int r = 0; r < 4; r++) {
        int row = q0 + wm + qi * 16 + quad * 4 + r;
        int col = h * HD + di * 16 + l15;
        O[(tokBase + row) * C + col] = f2bf(o[qi][di][r] * linv[qi][r]);
      }
}

extern "C" void kernel_launch(void* const* d_in, const int* in_sizes, int n_in,
                              void* d_out, int out_size, void* d_ws, size_t ws_size,
                              hipStream_t stream) {
  const float* x   = (const float*)d_in[0];
  const float* pos = (const float*)d_in[1];
  const float* nqg = (const float*)d_in[2];
  const float* nqb = (const float*)d_in[3];
  const float* nkg = (const float*)d_in[4];
  const float* nkb = (const float*)d_in[5];
  const float* nvg = (const float*)d_in[6];
  const float* nvb = (const float*)d_in[7];
  const float* ng  = (const float*)d_in[8];
  const float* nb  = (const float*)d_in[9];
  const float* wq  = (const float*)d_in[10];
  const float* bq  = (const float*)d_in[11];
  const float* wk  = (const float*)d_in[12];
  const float* bk  = (const float*)d_in[13];
  const float* wv  = (const float*)d_in[14];
  const float* bv  = (const float*)d_in[15];
  const float* wp  = (const float*)d_in[16];
  const float* bp  = (const float*)d_in[17];
  const float* w1  = (const float*)d_in[18];
  const float* b1  = (const float*)d_in[19];
  const float* w2  = (const float*)d_in[20];
  const float* b2  = (const float*)d_in[21];

  char* ws = (char*)d_ws;
  const size_t MB = 1u << 20;
  short* wqT  = (short*)(ws + 0 * MB);
  short* wkT  = (short*)(ws + 2 * MB);
  short* wvT  = (short*)(ws + 4 * MB);
  short* wpT  = (short*)(ws + 6 * MB);
  short* w1T  = (short*)(ws + 8 * MB);     // [HID][C]
  short* w2T  = (short*)(ws + 16 * MB);    // [C][HID]
  short* xq   = (short*)(ws + 24 * MB);
  short* xk   = (short*)(ws + 40 * MB);
  short* xv   = (short*)(ws + 56 * MB);
  short* Qm   = (short*)(ws + 72 * MB);
  short* Km   = (short*)(ws + 88 * MB);
  short* Vm   = (short*)(ws + 104 * MB);
  short* Vt   = (short*)(ws + 120 * MB);
  short* y1   = (short*)(ws + 72 * MB);    // overlays Q/K/V/Vt (dead after attn)
  short* Ob   = xk;                         // overlays xk (dead after K-proj)
  short* hln  = xq;                         // overlays xq (dead after Q-proj)
  float* hbuf = (float*)(ws + 136 * MB);
  (void)ws_size; (void)in_sizes; (void)n_in; (void)out_size;

  dim3 blk(256);
  k_transpose_w4<<<dim3(32, 32, 4), blk, 0, stream>>>(wq, wk, wv, wp, wqT, wkT, wvT, wpT);
  k_transpose_w<<<dim3(128, 32), blk, 0, stream>>>(w1, w1T, C, HID);
  k_transpose_w<<<dim3(32, 128), blk, 0, stream>>>(w2, w2T, HID, C);
  k_ln_qkv<<<dim3(MTOT), blk, 0, stream>>>(x, pos, nqg, nqb, nkg, nkb, nvg, nvb, xq, xk, xv);
  // QKV: gemm2 (z-stack gives 384 blocks; 2x-work tiles -> effective 3 work-rounds).
  k_gemm2_qkv<<<dim3(MTOT / 256, C / 256, 3), dim3(512), 0, stream>>>(
      xq, xk, xv, wqT, wkT, wvT, bq, bk, bv, Qm, Km, Vm);
  k_transpose_v<<<dim3(SEQ / 32, HD / 32, Bb * NH), blk, 0, stream>>>(Vm, Vt);
  // attn: r14-exact configuration (measured 94 us; session-best total 521.2).
  k_attn<<<dim3(Bb * NH, SEQ / 128), blk, 0, stream>>>(Qm, Km, Vt, Ob);
  // wp (N=1024): gemm8 — 256 blocks = 1/CU (gemm2 would starve at 128).
  k_gemm8<2><<<dim3(MTOT / 128, C / 256), dim3(512), 0, stream>>>(Ob, wpT, bp, x, hbuf, C, C);
  k_ln1<<<dim3(MTOT), blk, 0, stream>>>(hbuf, ng, nb, hln);
  // MLP1 (N=4096): gemm2 — 512 blocks = 2 full rounds of 2x-efficient tiles.
  k_gemm2<1><<<dim3(MTOT / 256, HID / 256), dim3(512), 0, stream>>>(hln, w1T, b1, nullptr,
                                                                    y1, HID, C);
  // MLP2 (N=1024): gemm8 — 256 blocks = 1/CU.
  k_gemm8<2><<<dim3(MTOT / 128, C / 256), dim3(512), 0, stream>>>(y1, w2T, b2, hbuf,
                                                                  (float*)d_out, C, HID);
}